// Round 1
// baseline (406.025 us; speedup 1.0000x reference)
//
#include <hip/hip_runtime.h>
#include <hip/hip_bf16.h>

constexpr int B  = 256;
constexpr int E  = 16384;
constexpr int M  = 65536;
constexpr int H  = 128;
constexpr int NH = 4;
constexpr int HD = 32;
constexpr int LQ = 128;
constexpr int LK = 384;

// ---------------- K1: segment starts via binary search ----------------
__global__ void k_starts(const int* __restrict__ eb, const int* __restrict__ ieb,
                         int* __restrict__ sq, int* __restrict__ sk) {
  int t = threadIdx.x;
  if (t <= B) {
    int lo = 0, hi = E;
    while (lo < hi) { int mid = (lo + hi) >> 1; if (eb[mid] < t) lo = mid + 1; else hi = mid; }
    sq[t] = lo;
    lo = 0; hi = M;
    while (lo < hi) { int mid = (lo + hi) >> 1; if (ieb[mid] < t) lo = mid + 1; else hi = mid; }
    sk[t] = lo;
  }
}

// ---------------- K2a: Q projection over E edge rows ----------------
// Qe[i] = edge_attr[i] @ wq.T + bq
template<int R>
__global__ void k_proj_q(const float* __restrict__ edge_attr,
                         const float* __restrict__ wq, const float* __restrict__ bq,
                         float* __restrict__ Qe) {
  __shared__ __align__(16) float in[R][H];
  const int t = threadIdx.x;           // 0..127 = output channel
  const int row0 = blockIdx.x * R;
  // stage R contiguous rows
  const float4* src = (const float4*)(edge_attr + (size_t)row0 * H);
  float4* dst = (float4*)&in[0][0];
  for (int k = t; k < R * (H / 4); k += 128) dst[k] = src[k];
  __syncthreads();
  float acc[R];
#pragma unroll
  for (int r = 0; r < R; r++) acc[r] = 0.f;
  const float4* w4 = (const float4*)(wq + (size_t)t * H);
  for (int j4 = 0; j4 < H / 4; j4++) {
    float4 w = w4[j4];
#pragma unroll
    for (int r = 0; r < R; r++) {
      float4 x = ((const float4*)&in[r][0])[j4];
      acc[r] += x.x * w.x + x.y * w.y + x.z * w.z + x.w * w.w;
    }
  }
  float bb = bq[t];
#pragma unroll
  for (int r = 0; r < R; r++) Qe[(size_t)(row0 + r) * H + t] = acc[r] + bb;
}

// ---------------- K2b: K,V projection over M gathered rows ----------------
// Km[j] = edge_attr[iel[j]] @ wk.T + bk ; Vm[j] = edge_attr[iel[j]] @ wv.T + bv
template<int R>
__global__ void k_proj_kv(const float* __restrict__ edge_attr, const int* __restrict__ iel,
                          const float* __restrict__ wk, const float* __restrict__ wv,
                          const float* __restrict__ bk, const float* __restrict__ bv,
                          float* __restrict__ Km, float* __restrict__ Vm) {
  __shared__ __align__(16) float in[R][H];
  const int t = threadIdx.x;           // 0..127 = output channel
  const int row0 = blockIdx.x * R;
  for (int k = t; k < R * (H / 4); k += 128) {
    int r = k >> 5, c = k & 31;
    int srow = iel[row0 + r];
    ((float4*)&in[r][0])[c] = ((const float4*)(edge_attr + (size_t)srow * H))[c];
  }
  __syncthreads();
  float acck[R], accv[R];
#pragma unroll
  for (int r = 0; r < R; r++) { acck[r] = 0.f; accv[r] = 0.f; }
  const float4* wk4 = (const float4*)(wk + (size_t)t * H);
  const float4* wv4 = (const float4*)(wv + (size_t)t * H);
  for (int j4 = 0; j4 < H / 4; j4++) {
    float4 a = wk4[j4];
    float4 b = wv4[j4];
#pragma unroll
    for (int r = 0; r < R; r++) {
      float4 x = ((const float4*)&in[r][0])[j4];
      acck[r] += x.x * a.x + x.y * a.y + x.z * a.z + x.w * a.w;
      accv[r] += x.x * b.x + x.y * b.y + x.z * b.z + x.w * b.w;
    }
  }
  float bbk = bk[t], bbv = bv[t];
#pragma unroll
  for (int r = 0; r < R; r++) {
    Km[(size_t)(row0 + r) * H + t] = acck[r] + bbk;
    Vm[(size_t)(row0 + r) * H + t] = accv[r] + bbv;
  }
}

// ---------------- K3: per-(batch,head) attention, online softmax ----------------
__global__ void k_attn(const float* __restrict__ Qe, const float* __restrict__ Km,
                       const float* __restrict__ Vm,
                       const int* __restrict__ sq, const int* __restrict__ sk,
                       const float* __restrict__ in_proj_b, float* __restrict__ Ctx) {
  constexpr int TILE = 64;
  __shared__ __align__(16) float Kt[TILE][HD];
  __shared__ __align__(16) float Vt[TILE][HD];
  const int b = blockIdx.x, h = blockIdx.y;
  const int t = threadIdx.x;           // 128 threads, one q slot each
  const int q0 = sq[b];
  const int lenq = sq[b + 1] - q0;
  const int nq = lenq < LQ ? lenq : LQ;
  const int k0 = sk[b];
  const int lenk = sk[b + 1] - k0;
  const int nk = lenk < LK ? lenk : LK;

  const bool active = t < nq;
  int qi = q0 + t;
  if (lenq > LQ && t == LQ - 1) qi = q0 + lenq - 1;  // last-writer-wins clip

  float4 q[8];
  if (active) {
    const float4* qs = (const float4*)(Qe + (size_t)qi * H + h * HD);
#pragma unroll
    for (int c = 0; c < 8; c++) q[c] = qs[c];
  }
  float m = -1e30f, s = 0.f;
  float acc[HD];
#pragma unroll
  for (int d = 0; d < HD; d++) acc[d] = 0.f;
  const float scale = 0.17677669529663687f;  // 1/sqrt(32)

  for (int kb = 0; kb < nk; kb += TILE) {
    int cnt = nk - kb; if (cnt > TILE) cnt = TILE;
    __syncthreads();
    for (int idx = t; idx < cnt * 8; idx += 128) {
      int j = idx >> 3, c = idx & 7;
      int slot = kb + j;
      int kj = k0 + slot;
      if (lenk > LK && slot == LK - 1) kj = k0 + lenk - 1;  // clip
      ((float4*)&Kt[j][0])[c] = ((const float4*)(Km + (size_t)kj * H + h * HD))[c];
      ((float4*)&Vt[j][0])[c] = ((const float4*)(Vm + (size_t)kj * H + h * HD))[c];
    }
    __syncthreads();
    if (active) {
      for (int j = 0; j < cnt; j++) {
        float logit = 0.f;
#pragma unroll
        for (int c = 0; c < 8; c++) {
          float4 kv = ((const float4*)&Kt[j][0])[c];
          logit += q[c].x * kv.x + q[c].y * kv.y + q[c].z * kv.z + q[c].w * kv.w;
        }
        logit *= scale;
        float w;
        if (logit > m) {
          float f = __expf(m - logit);
          s *= f;
#pragma unroll
          for (int d = 0; d < HD; d++) acc[d] *= f;
          m = logit;
          w = 1.f;
        } else {
          w = __expf(logit - m);
        }
        s += w;
#pragma unroll
        for (int d = 0; d < HD; d++) acc[d] += w * Vt[j][d];
      }
    }
  }

  if (active) {
    float* out = Ctx + (size_t)qi * H + h * HD;
    if (nk > 0) {
      float inv = 1.f / s;
#pragma unroll
      for (int d = 0; d < HD; d++) out[d] = acc[d] * inv;
    } else {
      // all-masked: softmax uniform over pad rows, v_pad = bv
      const float* bv = in_proj_b + 2 * H + h * HD;
#pragma unroll
      for (int d = 0; d < HD; d++) out[d] = bv[d];
    }
  }
}

// ---------------- K4: out-proj + residual + FFN ----------------
template<int R>
__global__ void k_out_ffn(const float* __restrict__ Ctx, const float* __restrict__ edge_attr,
                          const int* __restrict__ sq, const int* __restrict__ eb,
                          const float* __restrict__ opw, const float* __restrict__ opb,
                          const float* __restrict__ w1, const float* __restrict__ b1,
                          const float* __restrict__ w2, const float* __restrict__ b2,
                          float* __restrict__ out) {
  __shared__ __align__(16) float cL[R][H];
  __shared__ __align__(16) float aL[R][H];
  __shared__ __align__(16) float hL[R][2 * H];
  const int t = threadIdx.x;  // 256 threads
  const int row0 = blockIdx.x * R;

  // stage ctx rows (with q-clip source mapping)
  for (int k = t; k < R * (H / 4); k += 256) {
    int r = k >> 5, c = k & 31;
    int i = row0 + r;
    int bb = eb[i];
    int q0 = sq[bb];
    int lenq = sq[bb + 1] - q0;
    int src = i;
    if (lenq > LQ && (i - q0) >= LQ - 1) src = q0 + lenq - 1;
    ((float4*)&cL[r][0])[c] = ((const float4*)(Ctx + (size_t)src * H))[c];
  }
  __syncthreads();

  // phase 1: att = edge_attr + ctx @ opw.T + opb  (128 oc x 2 row-groups)
  {
    const int oc = t & (H - 1);
    const int rg = t >> 7;  // 0 or 1
    float acc[R / 2];
#pragma unroll
    for (int r = 0; r < R / 2; r++) acc[r] = 0.f;
    const float4* w4 = (const float4*)(opw + (size_t)oc * H);
    for (int j4 = 0; j4 < H / 4; j4++) {
      float4 w = w4[j4];
#pragma unroll
      for (int r = 0; r < R / 2; r++) {
        float4 x = ((const float4*)&cL[rg * (R / 2) + r][0])[j4];
        acc[r] += x.x * w.x + x.y * w.y + x.z * w.z + x.w * w.w;
      }
    }
    float bo = opb[oc];
#pragma unroll
    for (int r = 0; r < R / 2; r++) {
      int row = rg * (R / 2) + r;
      aL[row][oc] = edge_attr[(size_t)(row0 + row) * H + oc] + bo + acc[r];
    }
  }
  __syncthreads();

  // phase 2: h1 = relu(att @ w1.T + b1)  (256 oc, all R rows per thread)
  {
    float acc[R];
#pragma unroll
    for (int r = 0; r < R; r++) acc[r] = 0.f;
    const float4* w4 = (const float4*)(w1 + (size_t)t * H);
    for (int j4 = 0; j4 < H / 4; j4++) {
      float4 w = w4[j4];
#pragma unroll
      for (int r = 0; r < R; r++) {
        float4 x = ((const float4*)&aL[r][0])[j4];
        acc[r] += x.x * w.x + x.y * w.y + x.z * w.z + x.w * w.w;
      }
    }
    float bb = b1[t];
#pragma unroll
    for (int r = 0; r < R; r++) hL[r][t] = fmaxf(acc[r] + bb, 0.f);
  }
  __syncthreads();

  // phase 3: out = att + h1 @ w2.T + b2  (128 oc x 2 row-groups)
  {
    const int oc = t & (H - 1);
    const int rg = t >> 7;
    float acc[R / 2];
#pragma unroll
    for (int r = 0; r < R / 2; r++) acc[r] = 0.f;
    const float4* w4 = (const float4*)(w2 + (size_t)oc * (2 * H));
    for (int j4 = 0; j4 < (2 * H) / 4; j4++) {
      float4 w = w4[j4];
#pragma unroll
      for (int r = 0; r < R / 2; r++) {
        float4 x = ((const float4*)&hL[rg * (R / 2) + r][0])[j4];
        acc[r] += x.x * w.x + x.y * w.y + x.z * w.z + x.w * w.w;
      }
    }
    float bb = b2[oc];
#pragma unroll
    for (int r = 0; r < R / 2; r++) {
      int row = rg * (R / 2) + r;
      out[(size_t)(row0 + row) * H + oc] = aL[row][oc] + bb + acc[r];
    }
  }
}

extern "C" void kernel_launch(void* const* d_in, const int* in_sizes, int n_in,
                              void* d_out, int out_size, void* d_ws, size_t ws_size,
                              hipStream_t stream) {
  // inputs (setup_inputs order)
  const float* edge_attr = (const float*)d_in[1];
  const int*   iel       = (const int*)d_in[2];   // incoming_edges_list (M)
  const int*   ieb       = (const int*)d_in[3];   // incoming_edges_batch (M, sorted)
  const int*   eb        = (const int*)d_in[4];   // edge_batch (E, sorted)
  const float* in_proj_w = (const float*)d_in[5]; // (3H, H)
  const float* in_proj_b = (const float*)d_in[6]; // (3H,)
  const float* opw       = (const float*)d_in[7]; // (H, H)
  const float* opb       = (const float*)d_in[8];
  const float* w1        = (const float*)d_in[9]; // (2H, H)
  const float* b1        = (const float*)d_in[10];
  const float* w2        = (const float*)d_in[11];// (H, 2H)
  const float* b2        = (const float*)d_in[12];
  float* out = (float*)d_out;

  // workspace layout
  char* ws = (char*)d_ws;
  int* sq = (int*)ws;                      // (B+1) ints
  int* sk = (int*)(ws + 2048);             // (B+1) ints
  float* Qe  = (float*)(ws + 4096);        // E*H
  float* Km  = Qe + (size_t)E * H;         // M*H
  float* Vm  = Km + (size_t)M * H;         // M*H
  float* Ctx = Vm + (size_t)M * H;         // E*H

  const float* wq = in_proj_w;
  const float* wk = in_proj_w + (size_t)H * H;
  const float* wv = in_proj_w + (size_t)2 * H * H;
  const float* bq = in_proj_b;
  const float* bk = in_proj_b + H;
  const float* bv = in_proj_b + 2 * H;

  k_starts<<<dim3(1), dim3(320), 0, stream>>>(eb, ieb, sq, sk);
  k_proj_q<16><<<dim3(E / 16), dim3(128), 0, stream>>>(edge_attr, wq, bq, Qe);
  k_proj_kv<16><<<dim3(M / 16), dim3(128), 0, stream>>>(edge_attr, iel, wk, wv, bk, bv, Km, Vm);
  k_attn<<<dim3(B, NH), dim3(128), 0, stream>>>(Qe, Km, Vm, sq, sk, in_proj_b, Ctx);
  k_out_ffn<8><<<dim3(E / 8), dim3(256), 0, stream>>>(Ctx, edge_attr, sq, eb, opw, opb, w1, b1, w2, b2, out);
}

// Round 5
// 234.570 us; speedup vs baseline: 1.7309x; 1.7309x over previous
//
#include <hip/hip_runtime.h>
#include <hip/hip_bf16.h>

constexpr int B  = 256;
constexpr int E  = 16384;
constexpr int M  = 65536;
constexpr int H  = 128;
constexpr int NH = 4;
constexpr int HD = 32;
constexpr int LQ = 128;
constexpr int LK = 384;

typedef __attribute__((ext_vector_type(8))) short bf16x8;
typedef __attribute__((ext_vector_type(4))) float f32x4;

__device__ __forceinline__ ushort f2bf(float x) {
  union { float f; unsigned u; } v; v.f = x;
  unsigned r = (v.u + 0x7FFFu + ((v.u >> 16) & 1u)) >> 16;
  return (ushort)r;
}

// ---------------- K1: segment starts + bf16 weight prep ----------------
__global__ void k_starts_prep(const int* __restrict__ eb, const int* __restrict__ ieb,
                              int* __restrict__ sq, int* __restrict__ sk,
                              const float* __restrict__ in_proj_w, ushort* __restrict__ Wb) {
  const int bx = blockIdx.x, t = threadIdx.x;
  if (bx == 0) {
    if (t <= B) {
      int lo = 0, hi = E;
      while (lo < hi) { int mid = (lo + hi) >> 1; if (eb[mid] < t) lo = mid + 1; else hi = mid; }
      sq[t] = lo;
      lo = 0; hi = M;
      while (lo < hi) { int mid = (lo + hi) >> 1; if (ieb[mid] < t) lo = mid + 1; else hi = mid; }
      sk[t] = lo;
    }
  } else {
    int i = (bx - 1) * 320 + t;
    if (i < 2 * H * H) Wb[i] = f2bf(in_proj_w[H * H + i]);  // wk rows then wv rows
  }
}

// ---------------- K2a: Q projection over E edge rows (fp32 VALU) ----------------
template<int R>
__global__ void k_proj_q(const float* __restrict__ edge_attr,
                         const float* __restrict__ wq, const float* __restrict__ bq,
                         float* __restrict__ Qe) {
  __shared__ __align__(16) float in[R][H];
  const int t = threadIdx.x;           // 0..127 = output channel
  const int row0 = blockIdx.x * R;
  const float4* src = (const float4*)(edge_attr + (size_t)row0 * H);
  float4* dst = (float4*)&in[0][0];
  for (int k = t; k < R * (H / 4); k += 128) dst[k] = src[k];
  __syncthreads();
  float acc[R];
#pragma unroll
  for (int r = 0; r < R; r++) acc[r] = 0.f;
  const float4* w4 = (const float4*)(wq + (size_t)t * H);
  for (int j4 = 0; j4 < H / 4; j4++) {
    float4 w = w4[j4];
#pragma unroll
    for (int r = 0; r < R; r++) {
      float4 x = ((const float4*)&in[r][0])[j4];
      acc[r] += x.x * w.x + x.y * w.y + x.z * w.z + x.w * w.w;
    }
  }
  float bb = bq[t];
#pragma unroll
  for (int r = 0; r < R; r++) Qe[(size_t)(row0 + r) * H + t] = acc[r] + bb;
}

// ---------------- K2b: K,V projection via MFMA ----------------
// Block: 256 threads = 4 waves, 64 gathered rows; out tile 64 x 256 (wk|wv).
__global__ __launch_bounds__(256) void k_proj_kv_mfma(
    const float* __restrict__ edge_attr, const int* __restrict__ iel,
    const ushort* __restrict__ Wb, const float* __restrict__ in_proj_b,
    float* __restrict__ Km, float* __restrict__ Vm) {
  constexpr int RT = 64;
  constexpr int IP = 136;              // row pitch (bf16), 16B-aligned
  __shared__ ushort inL[RT * IP];      // 17408 B
  const int t = threadIdx.x;
  const int row0 = blockIdx.x * RT;
  // gather + cvt to bf16
  for (int idx = t; idx < RT * 32; idx += 256) {
    int r = idx >> 5, c = idx & 31;
    int srow = iel[row0 + r];
    float4 v = ((const float4*)(edge_attr + (size_t)srow * H))[c];
    ushort4 o; o.x = f2bf(v.x); o.y = f2bf(v.y); o.z = f2bf(v.z); o.w = f2bf(v.w);
    *(ushort4*)(inL + r * IP + c * 4) = o;
  }
  __syncthreads();
  const int wave = t >> 6, lane = t & 63, g = lane >> 4, l15 = lane & 15;
  // A-fragments: rows wave*16 + l15, k-slices kc*32 + 8g
  bf16x8 a[4];
#pragma unroll
  for (int kc = 0; kc < 4; kc++)
    a[kc] = *(const bf16x8*)(inL + (wave * 16 + l15) * IP + kc * 32 + g * 8);
  const float* bias = in_proj_b + H;   // bk (128) then bv (128)
#pragma unroll
  for (int ct = 0; ct < 16; ct++) {
    f32x4 acc = {0.f, 0.f, 0.f, 0.f};
#pragma unroll
    for (int kc = 0; kc < 4; kc++) {
      bf16x8 bfr = *(const bf16x8*)(Wb + (size_t)(ct * 16 + l15) * H + kc * 32 + g * 8);
      acc = __builtin_amdgcn_mfma_f32_16x16x32_bf16(a[kc], bfr, acc, 0, 0, 0);
    }
    int oc = ct * 16 + l15;            // D col = l15
    float bb = bias[oc];
    float* dst = (oc < H) ? (Km + (size_t)(row0 + wave * 16) * H + oc)
                          : (Vm + (size_t)(row0 + wave * 16) * H + (oc - H));
#pragma unroll
    for (int r = 0; r < 4; r++)        // D row = 4g + r
      dst[(size_t)(4 * g + r) * H] = acc[r] + bb;
  }
}

// ---------------- K3: MFMA flash attention (deterministic LDS) ----------------
__global__ __launch_bounds__(256) void k_attn_mfma(
    const float* __restrict__ Qe, const float* __restrict__ Km,
    const float* __restrict__ Vm, const int* __restrict__ sq,
    const int* __restrict__ sk, const float* __restrict__ in_proj_b,
    float* __restrict__ Ctx) {
  constexpr int KP = 40;
  constexpr int QP = 40;
  constexpr int VP = 392;
  constexpr int PP = 40;
  __shared__ ushort Kl[LK * KP];
  __shared__ ushort Ql[LQ * QP];
  __shared__ ushort VTl[HD * VP];
  __shared__ ushort Pl[4 * 16 * PP];

  const int b = blockIdx.x, h = blockIdx.y;
  const int t = threadIdx.x;
  const int q0 = sq[b], lenq = sq[b + 1] - q0;
  const int k0 = sk[b], lenk = sk[b + 1] - k0;
  const int nq = lenq < LQ ? lenq : LQ;
  const int nk = lenk < LK ? lenk : LK;
  const int nkc = (nk + 31) & ~31;
  const int nqt = (nq + 15) >> 4;
  ushort4 z4; z4.x = 0; z4.y = 0; z4.z = 0; z4.w = 0;

  // stage Q (bf16, row-major)
  for (int idx = t; idx < nq * 8; idx += 256) {
    int row = idx >> 3, c = idx & 7;
    int src = q0 + row;
    if (lenq > LQ && row == LQ - 1) src = q0 + lenq - 1;
    float4 v = *(const float4*)(Qe + (size_t)src * H + h * HD + c * 4);
    ushort4 o; o.x = f2bf(v.x); o.y = f2bf(v.y); o.z = f2bf(v.z); o.w = f2bf(v.w);
    *(ushort4*)(Ql + row * QP + c * 4) = o;
  }
  // zero Q pad rows [nq, nqt*16)
  for (int idx = t; idx < (nqt * 16 - nq) * 8; idx += 256) {
    int row = nq + (idx >> 3), c = idx & 7;
    *(ushort4*)(Ql + row * QP + c * 4) = z4;
  }
  // stage K (bf16, row-major)
  for (int idx = t; idx < nk * 8; idx += 256) {
    int row = idx >> 3, c = idx & 7;
    int src = k0 + row;
    if (lenk > LK && row == LK - 1) src = k0 + lenk - 1;
    float4 v = *(const float4*)(Km + (size_t)src * H + h * HD + c * 4);
    ushort4 o; o.x = f2bf(v.x); o.y = f2bf(v.y); o.z = f2bf(v.z); o.w = f2bf(v.w);
    *(ushort4*)(Kl + row * KP + c * 4) = o;
  }
  // zero K pad rows [nk, nkc)
  for (int idx = t; idx < (nkc - nk) * 8; idx += 256) {
    int row = nk + (idx >> 3), c = idx & 7;
    *(ushort4*)(Kl + row * KP + c * 4) = z4;
  }
  // stage V transposed (bf16): VTl[d][k] = V[k][d]
  for (int idx = t; idx < nk * 8; idx += 256) {
    int k = idx >> 3, c = idx & 7;
    int src = k0 + k;
    if (lenk > LK && k == LK - 1) src = k0 + lenk - 1;
    float4 v = *(const float4*)(Vm + (size_t)src * H + h * HD + c * 4);
    int d = c * 4;
    VTl[(d + 0) * VP + k] = f2bf(v.x);
    VTl[(d + 1) * VP + k] = f2bf(v.y);
    VTl[(d + 2) * VP + k] = f2bf(v.z);
    VTl[(d + 3) * VP + k] = f2bf(v.w);
  }
  // zero V^T pad columns [nk, nkc)
  for (int idx = t; idx < ((nkc - nk) << 5); idx += 256) {
    int d = idx & 31, k = nk + (idx >> 5);
    VTl[d * VP + k] = 0;
  }
  __syncthreads();

  const int wave = t >> 6, lane = t & 63, g = lane >> 4, l15 = lane & 15;
  ushort* Pw = Pl + wave * 16 * PP;
  const float scale = 0.17677669529663687f;  // 1/sqrt(32)

  for (int qt = wave; qt < nqt; qt += 4) {
    bf16x8 bq = *(const bf16x8*)(Ql + (qt * 16 + l15) * QP + g * 8);
    f32x4 o0 = {0.f, 0.f, 0.f, 0.f}, o1 = {0.f, 0.f, 0.f, 0.f};
    float m = -3.0e38f, s = 0.f;
    for (int kc = 0; kc < nk; kc += 32) {
      bf16x8 a0 = *(const bf16x8*)(Kl + (kc + l15) * KP + g * 8);
      bf16x8 a1 = *(const bf16x8*)(Kl + (kc + 16 + l15) * KP + g * 8);
      f32x4 z = {0.f, 0.f, 0.f, 0.f};
      f32x4 s0 = __builtin_amdgcn_mfma_f32_16x16x32_bf16(a0, bq, z, 0, 0, 0);
      f32x4 s1 = __builtin_amdgcn_mfma_f32_16x16x32_bf16(a1, bq, z, 0, 0, 0);
      float p[8];
#pragma unroll
      for (int r = 0; r < 4; r++) {
        p[r]     = (kc + 4 * g + r < nk)      ? s0[r] * scale : -1e30f;
        p[4 + r] = (kc + 16 + 4 * g + r < nk) ? s1[r] * scale : -1e30f;
      }
      float pm = p[0];
#pragma unroll
      for (int r = 1; r < 8; r++) pm = fmaxf(pm, p[r]);
      pm = fmaxf(pm, __shfl_xor(pm, 16));
      pm = fmaxf(pm, __shfl_xor(pm, 32));
      float mn = fmaxf(m, pm);
      float corr = __expf(m - mn);
      float rs = 0.f;
#pragma unroll
      for (int r = 0; r < 8; r++) { p[r] = __expf(p[r] - mn); rs += p[r]; }
      rs += __shfl_xor(rs, 16);
      rs += __shfl_xor(rs, 32);
      s = s * corr + rs;
      m = mn;
      ushort4 w0; w0.x = f2bf(p[0]); w0.y = f2bf(p[1]); w0.z = f2bf(p[2]); w0.w = f2bf(p[3]);
      ushort4 w1; w1.x = f2bf(p[4]); w1.y = f2bf(p[5]); w1.z = f2bf(p[6]); w1.w = f2bf(p[7]);
      __builtin_amdgcn_sched_barrier(0);
      *(ushort4*)(Pw + l15 * PP + 4 * g) = w0;
      *(ushort4*)(Pw + l15 * PP + 16 + 4 * g) = w1;
      asm volatile("s_waitcnt lgkmcnt(0)" ::: "memory");
      __builtin_amdgcn_sched_barrier(0);
      bf16x8 pb = *(const bf16x8*)(Pw + l15 * PP + 8 * g);
      bf16x8 av0 = *(const bf16x8*)(VTl + l15 * VP + kc + 8 * g);
      bf16x8 av1 = *(const bf16x8*)(VTl + (16 + l15) * VP + kc + 8 * g);
#pragma unroll
      for (int r = 0; r < 4; r++) { o0[r] *= corr; o1[r] *= corr; }
      o0 = __builtin_amdgcn_mfma_f32_16x16x32_bf16(av0, pb, o0, 0, 0, 0);
      o1 = __builtin_amdgcn_mfma_f32_16x16x32_bf16(av1, pb, o1, 0, 0, 0);
    }
    int slot = qt * 16 + l15;
    if (slot < nq) {
      int qi = q0 + slot;
      if (lenq > LQ && slot == LQ - 1) qi = q0 + lenq - 1;
      float* outp = Ctx + (size_t)qi * H + h * HD;
      if (nk > 0) {
        float inv = 1.f / s;
        float4 v0 = make_float4(o0[0] * inv, o0[1] * inv, o0[2] * inv, o0[3] * inv);
        float4 v1 = make_float4(o1[0] * inv, o1[1] * inv, o1[2] * inv, o1[3] * inv);
        *(float4*)(outp + 4 * g) = v0;
        *(float4*)(outp + 16 + 4 * g) = v1;
      } else {
        const float* bv = in_proj_b + 2 * H + h * HD;
        *(float4*)(outp + 4 * g) = *(const float4*)(bv + 4 * g);
        *(float4*)(outp + 16 + 4 * g) = *(const float4*)(bv + 16 + 4 * g);
      }
    }
  }
}

// ---------------- K4: out-proj + residual + FFN ----------------
template<int R>
__global__ void k_out_ffn(const float* __restrict__ Ctx, const float* __restrict__ edge_attr,
                          const int* __restrict__ sq, const int* __restrict__ eb,
                          const float* __restrict__ opw, const float* __restrict__ opb,
                          const float* __restrict__ w1, const float* __restrict__ b1,
                          const float* __restrict__ w2, const float* __restrict__ b2,
                          float* __restrict__ out) {
  __shared__ __align__(16) float cL[R][H];
  __shared__ __align__(16) float aL[R][H];
  __shared__ __align__(16) float hL[R][2 * H];
  const int t = threadIdx.x;  // 256 threads
  const int row0 = blockIdx.x * R;

  for (int k = t; k < R * (H / 4); k += 256) {
    int r = k >> 5, c = k & 31;
    int i = row0 + r;
    int bb = eb[i];
    int q0 = sq[bb];
    int lenq = sq[bb + 1] - q0;
    int src = i;
    if (lenq > LQ && (i - q0) >= LQ - 1) src = q0 + lenq - 1;
    ((float4*)&cL[r][0])[c] = ((const float4*)(Ctx + (size_t)src * H))[c];
  }
  __syncthreads();

  {
    const int oc = t & (H - 1);
    const int rg = t >> 7;
    float acc[R / 2];
#pragma unroll
    for (int r = 0; r < R / 2; r++) acc[r] = 0.f;
    const float4* w4 = (const float4*)(opw + (size_t)oc * H);
    for (int j4 = 0; j4 < H / 4; j4++) {
      float4 w = w4[j4];
#pragma unroll
      for (int r = 0; r < R / 2; r++) {
        float4 x = ((const float4*)&cL[rg * (R / 2) + r][0])[j4];
        acc[r] += x.x * w.x + x.y * w.y + x.z * w.z + x.w * w.w;
      }
    }
    float bo = opb[oc];
#pragma unroll
    for (int r = 0; r < R / 2; r++) {
      int row = rg * (R / 2) + r;
      aL[row][oc] = edge_attr[(size_t)(row0 + row) * H + oc] + bo + acc[r];
    }
  }
  __syncthreads();

  {
    float acc[R];
#pragma unroll
    for (int r = 0; r < R; r++) acc[r] = 0.f;
    const float4* w4 = (const float4*)(w1 + (size_t)t * H);
    for (int j4 = 0; j4 < H / 4; j4++) {
      float4 w = w4[j4];
#pragma unroll
      for (int r = 0; r < R; r++) {
        float4 x = ((const float4*)&aL[r][0])[j4];
        acc[r] += x.x * w.x + x.y * w.y + x.z * w.z + x.w * w.w;
      }
    }
    float bb = b1[t];
#pragma unroll
    for (int r = 0; r < R; r++) hL[r][t] = fmaxf(acc[r] + bb, 0.f);
  }
  __syncthreads();

  {
    const int oc = t & (H - 1);
    const int rg = t >> 7;
    float acc[R / 2];
#pragma unroll
    for (int r = 0; r < R / 2; r++) acc[r] = 0.f;
    const float4* w4 = (const float4*)(w2 + (size_t)oc * (2 * H));
    for (int j4 = 0; j4 < (2 * H) / 4; j4++) {
      float4 w = w4[j4];
#pragma unroll
      for (int r = 0; r < R / 2; r++) {
        float4 x = ((const float4*)&hL[rg * (R / 2) + r][0])[j4];
        acc[r] += x.x * w.x + x.y * w.y + x.z * w.z + x.w * w.w;
      }
    }
    float bb = b2[oc];
#pragma unroll
    for (int r = 0; r < R / 2; r++) {
      int row = rg * (R / 2) + r;
      out[(size_t)(row0 + row) * H + oc] = aL[row][oc] + bb + acc[r];
    }
  }
}

extern "C" void kernel_launch(void* const* d_in, const int* in_sizes, int n_in,
                              void* d_out, int out_size, void* d_ws, size_t ws_size,
                              hipStream_t stream) {
  const float* edge_attr = (const float*)d_in[1];
  const int*   iel       = (const int*)d_in[2];
  const int*   ieb       = (const int*)d_in[3];
  const int*   eb        = (const int*)d_in[4];
  const float* in_proj_w = (const float*)d_in[5];
  const float* in_proj_b = (const float*)d_in[6];
  const float* opw       = (const float*)d_in[7];
  const float* opb       = (const float*)d_in[8];
  const float* w1        = (const float*)d_in[9];
  const float* b1        = (const float*)d_in[10];
  const float* w2        = (const float*)d_in[11];
  const float* b2        = (const float*)d_in[12];
  float* out = (float*)d_out;

  char* ws = (char*)d_ws;
  int* sq = (int*)ws;
  int* sk = (int*)(ws + 2048);
  float* Qe  = (float*)(ws + 4096);
  float* Km  = Qe + (size_t)E * H;
  float* Vm  = Km + (size_t)M * H;
  float* Ctx = Vm + (size_t)M * H;
  ushort* Wb = (ushort*)(Ctx + (size_t)E * H);  // 2H x H bf16 (wk|wv)

  const float* wq = in_proj_w;
  const float* bq = in_proj_b;

  k_starts_prep<<<dim3(104), dim3(320), 0, stream>>>(eb, ieb, sq, sk, in_proj_w, Wb);
  k_proj_q<16><<<dim3(E / 16), dim3(128), 0, stream>>>(edge_attr, wq, bq, Qe);
  k_proj_kv_mfma<<<dim3(M / 64), dim3(256), 0, stream>>>(edge_attr, iel, Wb, in_proj_b, Km, Vm);
  k_attn_mfma<<<dim3(B, NH), dim3(256), 0, stream>>>(Qe, Km, Vm, sq, sk, in_proj_b, Ctx);
  k_out_ffn<8><<<dim3(E / 8), dim3(256), 0, stream>>>(Ctx, edge_attr, sq, eb, opw, opb, w1, b1, w2, b2, out);
}

// Round 6
// 141.957 us; speedup vs baseline: 2.8602x; 1.6524x over previous
//
#include <hip/hip_runtime.h>
#include <hip/hip_bf16.h>

constexpr int B  = 256;
constexpr int E  = 16384;
constexpr int M  = 65536;
constexpr int H  = 128;
constexpr int NH = 4;
constexpr int HD = 32;
constexpr int LQ = 128;
constexpr int LK = 384;

// bf16 weight buffer offsets (elements)
constexpr int WQ_OFF  = 0;
constexpr int WK_OFF  = 16384;
constexpr int WV_OFF  = 32768;
constexpr int OPW_OFF = 49152;
constexpr int W1_OFF  = 65536;
constexpr int W2_OFF  = 98304;
constexpr int W_TOTAL = 131072;

typedef __attribute__((ext_vector_type(8))) short bf16x8;
typedef __attribute__((ext_vector_type(8))) unsigned short u16x8;
typedef __attribute__((ext_vector_type(4))) float f32x4;

__device__ __forceinline__ ushort f2bf(float x) {
  union { float f; unsigned u; } v; v.f = x;
  unsigned r = (v.u + 0x7FFFu + ((v.u >> 16) & 1u)) >> 16;
  return (ushort)r;
}

// ---------------- K1: segment starts + bf16 weight prep ----------------
__global__ __launch_bounds__(256) void k_starts_prep(
    const int* __restrict__ eb, const int* __restrict__ ieb,
    int* __restrict__ sq, int* __restrict__ sk,
    const float* __restrict__ in_proj_w, const float* __restrict__ opw,
    const float* __restrict__ w1, const float* __restrict__ w2,
    ushort* __restrict__ Wb) {
  const int bx = blockIdx.x, t = threadIdx.x;
  if (bx == 0) {
    for (int i = t; i <= B; i += 256) {
      int lo = 0, hi = E;
      while (lo < hi) { int mid = (lo + hi) >> 1; if (eb[mid] < i) lo = mid + 1; else hi = mid; }
      sq[i] = lo;
      lo = 0; hi = M;
      while (lo < hi) { int mid = (lo + hi) >> 1; if (ieb[mid] < i) lo = mid + 1; else hi = mid; }
      sk[i] = lo;
    }
  } else {
    int i = ((bx - 1) * 256 + t) * 4;
    if (i < W_TOTAL) {
      float4 v;
      if (i < OPW_OFF)      v = *(const float4*)(in_proj_w + i);
      else if (i < W1_OFF)  v = *(const float4*)(opw + (i - OPW_OFF));
      else if (i < W2_OFF)  v = *(const float4*)(w1 + (i - W1_OFF));
      else                  v = *(const float4*)(w2 + (i - W2_OFF));
      ushort4 o; o.x = f2bf(v.x); o.y = f2bf(v.y); o.z = f2bf(v.z); o.w = f2bf(v.w);
      *(ushort4*)(Wb + i) = o;
    }
  }
}

// ---------------- K2a: Q projection via MFMA, bf16 out ----------------
__global__ __launch_bounds__(256) void k_proj_q_mfma(
    const float* __restrict__ edge_attr, const ushort* __restrict__ Wb,
    const float* __restrict__ in_proj_b, ushort* __restrict__ Qb) {
  constexpr int IP = 136;
  __shared__ ushort inL[64 * IP];   // 17408 B; reused as outL
  const int t = threadIdx.x;
  const int row0 = blockIdx.x * 64;
  for (int idx = t; idx < 64 * 32; idx += 256) {
    int r = idx >> 5, c = idx & 31;
    float4 v = ((const float4*)(edge_attr + (size_t)(row0 + r) * H))[c];
    ushort4 o; o.x = f2bf(v.x); o.y = f2bf(v.y); o.z = f2bf(v.z); o.w = f2bf(v.w);
    *(ushort4*)(inL + r * IP + c * 4) = o;
  }
  __syncthreads();
  const int w = t >> 6, lane = t & 63, g = lane >> 4, l15 = lane & 15;
  bf16x8 a[4];
#pragma unroll
  for (int kc = 0; kc < 4; kc++)
    a[kc] = *(const bf16x8*)(inL + (w * 16 + l15) * IP + kc * 32 + g * 8);
  __syncthreads();
  const float* bq = in_proj_b;
#pragma unroll
  for (int ct = 0; ct < 8; ct++) {
    f32x4 acc = {0.f, 0.f, 0.f, 0.f};
#pragma unroll
    for (int kc = 0; kc < 4; kc++) {
      bf16x8 bw = *(const bf16x8*)(Wb + WQ_OFF + (size_t)(ct * 16 + l15) * H + kc * 32 + g * 8);
      acc = __builtin_amdgcn_mfma_f32_16x16x32_bf16(a[kc], bw, acc, 0, 0, 0);
    }
    int oc = ct * 16 + l15;
    float bb = bq[oc];
#pragma unroll
    for (int r = 0; r < 4; r++)
      inL[(w * 16 + 4 * g + r) * IP + oc] = f2bf(acc[r] + bb);
  }
  __syncthreads();
  for (int idx = t; idx < 64 * 16; idx += 256) {
    int r = idx >> 4, c = idx & 15;
    *(u16x8*)(Qb + (size_t)(row0 + r) * H + c * 8) = *(const u16x8*)(inL + r * IP + c * 8);
  }
}

// ---------------- K2b: K,V projection via MFMA, bf16 out ----------------
__global__ __launch_bounds__(256) void k_proj_kv_mfma(
    const float* __restrict__ edge_attr, const int* __restrict__ iel,
    const ushort* __restrict__ Wb, const float* __restrict__ in_proj_b,
    ushort* __restrict__ Kb, ushort* __restrict__ Vb) {
  constexpr int IP = 136;
  __shared__ ushort inL[64 * IP];
  __shared__ ushort outL[64 * IP];
  const int t = threadIdx.x;
  const int row0 = blockIdx.x * 64;
  for (int idx = t; idx < 64 * 32; idx += 256) {
    int r = idx >> 5, c = idx & 31;
    int srow = iel[row0 + r];
    float4 v = ((const float4*)(edge_attr + (size_t)srow * H))[c];
    ushort4 o; o.x = f2bf(v.x); o.y = f2bf(v.y); o.z = f2bf(v.z); o.w = f2bf(v.w);
    *(ushort4*)(inL + r * IP + c * 4) = o;
  }
  __syncthreads();
  const int w = t >> 6, lane = t & 63, g = lane >> 4, l15 = lane & 15;
  bf16x8 a[4];
#pragma unroll
  for (int kc = 0; kc < 4; kc++)
    a[kc] = *(const bf16x8*)(inL + (w * 16 + l15) * IP + kc * 32 + g * 8);
#pragma unroll
  for (int pass = 0; pass < 2; pass++) {
    const int woff = pass == 0 ? WK_OFF : WV_OFF;
    const float* bias = in_proj_b + H + pass * H;
    ushort* dstg = pass == 0 ? Kb : Vb;
#pragma unroll
    for (int ct = 0; ct < 8; ct++) {
      f32x4 acc = {0.f, 0.f, 0.f, 0.f};
#pragma unroll
      for (int kc = 0; kc < 4; kc++) {
        bf16x8 bw = *(const bf16x8*)(Wb + woff + (size_t)(ct * 16 + l15) * H + kc * 32 + g * 8);
        acc = __builtin_amdgcn_mfma_f32_16x16x32_bf16(a[kc], bw, acc, 0, 0, 0);
      }
      int oc = ct * 16 + l15;
      float bb = bias[oc];
#pragma unroll
      for (int r = 0; r < 4; r++)
        outL[(w * 16 + 4 * g + r) * IP + oc] = f2bf(acc[r] + bb);
    }
    __syncthreads();
    for (int idx = t; idx < 64 * 16; idx += 256) {
      int r = idx >> 4, c = idx & 15;
      *(u16x8*)(dstg + (size_t)(row0 + r) * H + c * 8) = *(const u16x8*)(outL + r * IP + c * 8);
    }
    __syncthreads();
  }
}

// ---------------- K3: MFMA flash attention (bf16 in/out) ----------------
__global__ __launch_bounds__(256) void k_attn_mfma(
    const ushort* __restrict__ Qb, const ushort* __restrict__ Kb,
    const ushort* __restrict__ Vb, const int* __restrict__ sq,
    const int* __restrict__ sk, const float* __restrict__ in_proj_b,
    ushort* __restrict__ CtxB) {
  constexpr int KP = 40;
  constexpr int QP = 40;
  constexpr int VP = 392;
  constexpr int PP = 40;
  __shared__ ushort Kl[LK * KP];
  __shared__ ushort Ql[LQ * QP];
  __shared__ ushort VTl[HD * VP];
  __shared__ ushort Pl[4 * 16 * PP];

  const int b = blockIdx.x, h = blockIdx.y;
  const int t = threadIdx.x;
  const int q0 = sq[b], lenq = sq[b + 1] - q0;
  const int k0 = sk[b], lenk = sk[b + 1] - k0;
  const int nq = lenq < LQ ? lenq : LQ;
  const int nk = lenk < LK ? lenk : LK;
  const int nkc = (nk + 31) & ~31;
  const int nqt = (nq + 15) >> 4;
  u16x8 z8 = {0, 0, 0, 0, 0, 0, 0, 0};

  // stage Q
  for (int idx = t; idx < nq * 4; idx += 256) {
    int row = idx >> 2, c = idx & 3;
    int src = q0 + row;
    if (lenq > LQ && row == LQ - 1) src = q0 + lenq - 1;
    *(u16x8*)(Ql + row * QP + c * 8) = *(const u16x8*)(Qb + (size_t)src * H + h * HD + c * 8);
  }
  for (int idx = t; idx < (nqt * 16 - nq) * 4; idx += 256) {
    int row = nq + (idx >> 2), c = idx & 3;
    *(u16x8*)(Ql + row * QP + c * 8) = z8;
  }
  // stage K
  for (int idx = t; idx < nk * 4; idx += 256) {
    int row = idx >> 2, c = idx & 3;
    int src = k0 + row;
    if (lenk > LK && row == LK - 1) src = k0 + lenk - 1;
    *(u16x8*)(Kl + row * KP + c * 8) = *(const u16x8*)(Kb + (size_t)src * H + h * HD + c * 8);
  }
  for (int idx = t; idx < (nkc - nk) * 4; idx += 256) {
    int row = nk + (idx >> 2), c = idx & 3;
    *(u16x8*)(Kl + row * KP + c * 8) = z8;
  }
  // stage V transposed
  for (int idx = t; idx < nk * 4; idx += 256) {
    int k = idx >> 2, c = idx & 3;
    int src = k0 + k;
    if (lenk > LK && k == LK - 1) src = k0 + lenk - 1;
    u16x8 v = *(const u16x8*)(Vb + (size_t)src * H + h * HD + c * 8);
#pragma unroll
    for (int j = 0; j < 8; j++) VTl[(c * 8 + j) * VP + k] = v[j];
  }
  for (int idx = t; idx < ((nkc - nk) << 5); idx += 256) {
    int d = idx & 31, k = nk + (idx >> 5);
    VTl[d * VP + k] = 0;
  }
  __syncthreads();

  const int wave = t >> 6, lane = t & 63, g = lane >> 4, l15 = lane & 15;
  ushort* Pw = Pl + wave * 16 * PP;
  const float scale = 0.17677669529663687f;  // 1/sqrt(32)

  for (int qt = wave; qt < nqt; qt += 4) {
    bf16x8 bq = *(const bf16x8*)(Ql + (qt * 16 + l15) * QP + g * 8);
    f32x4 o0 = {0.f, 0.f, 0.f, 0.f}, o1 = {0.f, 0.f, 0.f, 0.f};
    float m = -3.0e38f, s = 0.f;
    for (int kc = 0; kc < nk; kc += 32) {
      bf16x8 a0 = *(const bf16x8*)(Kl + (kc + l15) * KP + g * 8);
      bf16x8 a1 = *(const bf16x8*)(Kl + (kc + 16 + l15) * KP + g * 8);
      f32x4 z = {0.f, 0.f, 0.f, 0.f};
      f32x4 s0 = __builtin_amdgcn_mfma_f32_16x16x32_bf16(a0, bq, z, 0, 0, 0);
      f32x4 s1 = __builtin_amdgcn_mfma_f32_16x16x32_bf16(a1, bq, z, 0, 0, 0);
      float p[8];
#pragma unroll
      for (int r = 0; r < 4; r++) {
        p[r]     = (kc + 4 * g + r < nk)      ? s0[r] * scale : -1e30f;
        p[4 + r] = (kc + 16 + 4 * g + r < nk) ? s1[r] * scale : -1e30f;
      }
      float pm = p[0];
#pragma unroll
      for (int r = 1; r < 8; r++) pm = fmaxf(pm, p[r]);
      pm = fmaxf(pm, __shfl_xor(pm, 16));
      pm = fmaxf(pm, __shfl_xor(pm, 32));
      float mn = fmaxf(m, pm);
      float corr = __expf(m - mn);
      float rs = 0.f;
#pragma unroll
      for (int r = 0; r < 8; r++) { p[r] = __expf(p[r] - mn); rs += p[r]; }
      rs += __shfl_xor(rs, 16);
      rs += __shfl_xor(rs, 32);
      s = s * corr + rs;
      m = mn;
      ushort4 w0; w0.x = f2bf(p[0]); w0.y = f2bf(p[1]); w0.z = f2bf(p[2]); w0.w = f2bf(p[3]);
      ushort4 w1; w1.x = f2bf(p[4]); w1.y = f2bf(p[5]); w1.z = f2bf(p[6]); w1.w = f2bf(p[7]);
      __builtin_amdgcn_sched_barrier(0);
      *(ushort4*)(Pw + l15 * PP + 4 * g) = w0;
      *(ushort4*)(Pw + l15 * PP + 16 + 4 * g) = w1;
      asm volatile("s_waitcnt lgkmcnt(0)" ::: "memory");
      __builtin_amdgcn_sched_barrier(0);
      bf16x8 pb = *(const bf16x8*)(Pw + l15 * PP + 8 * g);
      bf16x8 av0 = *(const bf16x8*)(VTl + l15 * VP + kc + 8 * g);
      bf16x8 av1 = *(const bf16x8*)(VTl + (16 + l15) * VP + kc + 8 * g);
#pragma unroll
      for (int r = 0; r < 4; r++) { o0[r] *= corr; o1[r] *= corr; }
      o0 = __builtin_amdgcn_mfma_f32_16x16x32_bf16(av0, pb, o0, 0, 0, 0);
      o1 = __builtin_amdgcn_mfma_f32_16x16x32_bf16(av1, pb, o1, 0, 0, 0);
    }
    int slot = qt * 16 + l15;
    if (slot < nq) {
      int qi = q0 + slot;
      if (lenq > LQ && slot == LQ - 1) qi = q0 + lenq - 1;
      ushort* outp = CtxB + (size_t)qi * H + h * HD;
      if (nk > 0) {
        float inv = 1.f / s;
        ushort4 v0, v1;
#pragma unroll
        for (int r = 0; r < 4; r++) { ((ushort*)&v0)[r] = f2bf(o0[r] * inv); ((ushort*)&v1)[r] = f2bf(o1[r] * inv); }
        *(ushort4*)(outp + 4 * g) = v0;
        *(ushort4*)(outp + 16 + 4 * g) = v1;
      } else {
        const float* bv = in_proj_b + 2 * H + h * HD;
        ushort4 v0, v1;
#pragma unroll
        for (int r = 0; r < 4; r++) { ((ushort*)&v0)[r] = f2bf(bv[4 * g + r]); ((ushort*)&v1)[r] = f2bf(bv[16 + 4 * g + r]); }
        *(ushort4*)(outp + 4 * g) = v0;
        *(ushort4*)(outp + 16 + 4 * g) = v1;
      }
    }
  }
}

// ---------------- K4: out-proj + residual + FFN via MFMA ----------------
__global__ __launch_bounds__(256) void k_out_ffn_mfma(
    const ushort* __restrict__ CtxB, const float* __restrict__ edge_attr,
    const int* __restrict__ sq, const int* __restrict__ eb,
    const ushort* __restrict__ Wb, const float* __restrict__ opb,
    const float* __restrict__ b1, const float* __restrict__ b2,
    float* __restrict__ out) {
  constexpr int IP = 136;  // K=128 pitch
  constexpr int HP = 264;  // K=256 pitch
  __shared__ ushort reg0[64 * HP];   // CtxL (64*IP) then h1 (64*HP)
  __shared__ ushort attB[64 * IP];
  const int t = threadIdx.x;
  const int row0 = blockIdx.x * 64;

  // stage ctx rows bf16 (with q-clip source mapping)
  for (int idx = t; idx < 64 * 16; idx += 256) {
    int r = idx >> 4, c = idx & 15;
    int i = row0 + r;
    int bb = eb[i];
    int qq0 = sq[bb];
    int lenq = sq[bb + 1] - qq0;
    int src = i;
    if (lenq > LQ && (i - qq0) >= LQ - 1) src = qq0 + lenq - 1;
    *(u16x8*)(reg0 + r * IP + c * 8) = *(const u16x8*)(CtxB + (size_t)src * H + c * 8);
  }
  __syncthreads();

  const int w = t >> 6, lane = t & 63, g = lane >> 4, l15 = lane & 15;
  const int wr = w * 16;
  bf16x8 ca[4];
#pragma unroll
  for (int kc = 0; kc < 4; kc++)
    ca[kc] = *(const bf16x8*)(reg0 + (wr + l15) * IP + kc * 32 + g * 8);
  __syncthreads();   // after this, reg0 is free for h1

  // phase A: att = ctx @ opw^T + opb + edge_attr (kept in registers + bf16 LDS)
  float att[8][4];
#pragma unroll
  for (int ct = 0; ct < 8; ct++) {
    f32x4 acc = {0.f, 0.f, 0.f, 0.f};
#pragma unroll
    for (int kc = 0; kc < 4; kc++) {
      bf16x8 bw = *(const bf16x8*)(Wb + OPW_OFF + (size_t)(ct * 16 + l15) * H + kc * 32 + g * 8);
      acc = __builtin_amdgcn_mfma_f32_16x16x32_bf16(ca[kc], bw, acc, 0, 0, 0);
    }
    int oc = ct * 16 + l15;
    float bo = opb[oc];
#pragma unroll
    for (int r = 0; r < 4; r++) {
      float v = acc[r] + bo + edge_attr[(size_t)(row0 + wr + 4 * g + r) * H + oc];
      att[ct][r] = v;
      attB[(wr + 4 * g + r) * IP + oc] = f2bf(v);
    }
  }

  // phase B: h1 = relu(att @ w1^T + b1) -> bf16 LDS (reg0)
  bf16x8 aa[4];
#pragma unroll
  for (int kc = 0; kc < 4; kc++)
    aa[kc] = *(const bf16x8*)(attB + (wr + l15) * IP + kc * 32 + g * 8);
#pragma unroll
  for (int ct = 0; ct < 16; ct++) {
    f32x4 acc = {0.f, 0.f, 0.f, 0.f};
#pragma unroll
    for (int kc = 0; kc < 4; kc++) {
      bf16x8 bw = *(const bf16x8*)(Wb + W1_OFF + (size_t)(ct * 16 + l15) * H + kc * 32 + g * 8);
      acc = __builtin_amdgcn_mfma_f32_16x16x32_bf16(aa[kc], bw, acc, 0, 0, 0);
    }
    int oc = ct * 16 + l15;
    float bb = b1[oc];
#pragma unroll
    for (int r = 0; r < 4; r++)
      reg0[(wr + 4 * g + r) * HP + oc] = f2bf(fmaxf(acc[r] + bb, 0.f));
  }

  // phase C: out = att + h1 @ w2^T + b2
  bf16x8 ha[8];
#pragma unroll
  for (int kc = 0; kc < 8; kc++)
    ha[kc] = *(const bf16x8*)(reg0 + (wr + l15) * HP + kc * 32 + g * 8);
#pragma unroll
  for (int ct = 0; ct < 8; ct++) {
    f32x4 acc = {0.f, 0.f, 0.f, 0.f};
#pragma unroll
    for (int kc = 0; kc < 8; kc++) {
      bf16x8 bw = *(const bf16x8*)(Wb + W2_OFF + (size_t)(ct * 16 + l15) * 2 * H + kc * 32 + g * 8);
      acc = __builtin_amdgcn_mfma_f32_16x16x32_bf16(ha[kc], bw, acc, 0, 0, 0);
    }
    int oc = ct * 16 + l15;
    float bb = b2[oc];
#pragma unroll
    for (int r = 0; r < 4; r++)
      out[(size_t)(row0 + wr + 4 * g + r) * H + oc] = att[ct][r] + acc[r] + bb;
  }
}

extern "C" void kernel_launch(void* const* d_in, const int* in_sizes, int n_in,
                              void* d_out, int out_size, void* d_ws, size_t ws_size,
                              hipStream_t stream) {
  const float* edge_attr = (const float*)d_in[1];
  const int*   iel       = (const int*)d_in[2];
  const int*   ieb       = (const int*)d_in[3];
  const int*   eb        = (const int*)d_in[4];
  const float* in_proj_w = (const float*)d_in[5];
  const float* in_proj_b = (const float*)d_in[6];
  const float* opw       = (const float*)d_in[7];
  const float* opb       = (const float*)d_in[8];
  const float* w1        = (const float*)d_in[9];
  const float* b1        = (const float*)d_in[10];
  const float* w2        = (const float*)d_in[11];
  const float* b2        = (const float*)d_in[12];
  float* out = (float*)d_out;

  char* ws = (char*)d_ws;
  int* sq = (int*)ws;
  int* sk = (int*)(ws + 2048);
  ushort* Qb   = (ushort*)(ws + 4096);            // E*H bf16
  ushort* Kb   = Qb + (size_t)E * H;              // M*H bf16
  ushort* Vb   = Kb + (size_t)M * H;              // M*H bf16
  ushort* CtxB = Vb + (size_t)M * H;              // E*H bf16
  ushort* Wb   = CtxB + (size_t)E * H;            // 131072 bf16 weights

  k_starts_prep<<<dim3(129), dim3(256), 0, stream>>>(eb, ieb, sq, sk, in_proj_w, opw, w1, w2, Wb);
  k_proj_q_mfma<<<dim3(E / 64), dim3(256), 0, stream>>>(edge_attr, Wb, in_proj_b, Qb);
  k_proj_kv_mfma<<<dim3(M / 64), dim3(256), 0, stream>>>(edge_attr, iel, Wb, in_proj_b, Kb, Vb);
  k_attn_mfma<<<dim3(B, NH), dim3(256), 0, stream>>>(Qb, Kb, Vb, sq, sk, in_proj_b, CtxB);
  k_out_ffn_mfma<<<dim3(E / 64), dim3(256), 0, stream>>>(CtxB, edge_attr, sq, eb, Wb, opb, b1, b2, out);
}

// Round 7
// 123.303 us; speedup vs baseline: 3.2929x; 1.1513x over previous
//
#include <hip/hip_runtime.h>
#include <hip/hip_bf16.h>

constexpr int B  = 256;
constexpr int E  = 16384;
constexpr int M  = 65536;
constexpr int H  = 128;
constexpr int NH = 4;
constexpr int HD = 32;
constexpr int LQ = 128;
constexpr int LK = 384;

// bf16 weight buffer offsets (elements)
constexpr int WQ_OFF  = 0;
constexpr int WK_OFF  = 16384;
constexpr int WV_OFF  = 32768;
constexpr int OPW_OFF = 49152;
constexpr int W1_OFF  = 65536;
constexpr int W2_OFF  = 98304;
constexpr int W_TOTAL = 131072;

typedef __attribute__((ext_vector_type(8))) short bf16x8;
typedef __attribute__((ext_vector_type(8))) unsigned short u16x8;
typedef __attribute__((ext_vector_type(4))) float f32x4;

__device__ __forceinline__ ushort f2bf(float x) {
  union { float f; unsigned u; } v; v.f = x;
  unsigned r = (v.u + 0x7FFFu + ((v.u >> 16) & 1u)) >> 16;
  return (ushort)r;
}

// ---------------- K1: segment starts + bf16 weight prep ----------------
__global__ __launch_bounds__(256) void k_starts_prep(
    const int* __restrict__ eb, const int* __restrict__ ieb,
    int* __restrict__ sq, int* __restrict__ sk,
    const float* __restrict__ in_proj_w, const float* __restrict__ opw,
    const float* __restrict__ w1, const float* __restrict__ w2,
    ushort* __restrict__ Wb) {
  const int bx = blockIdx.x, t = threadIdx.x;
  if (bx == 0) {
    for (int i = t; i <= B; i += 256) {
      int lo = 0, hi = E;
      while (lo < hi) { int mid = (lo + hi) >> 1; if (eb[mid] < i) lo = mid + 1; else hi = mid; }
      sq[i] = lo;
      lo = 0; hi = M;
      while (lo < hi) { int mid = (lo + hi) >> 1; if (ieb[mid] < i) lo = mid + 1; else hi = mid; }
      sk[i] = lo;
    }
  } else {
    int i = ((bx - 1) * 256 + t) * 4;
    if (i < W_TOTAL) {
      float4 v;
      if (i < OPW_OFF)      v = *(const float4*)(in_proj_w + i);
      else if (i < W1_OFF)  v = *(const float4*)(opw + (i - OPW_OFF));
      else if (i < W2_OFF)  v = *(const float4*)(w1 + (i - W1_OFF));
      else                  v = *(const float4*)(w2 + (i - W2_OFF));
      ushort4 o; o.x = f2bf(v.x); o.y = f2bf(v.y); o.z = f2bf(v.z); o.w = f2bf(v.w);
      *(ushort4*)(Wb + i) = o;
    }
  }
}

// ---------------- K2a: Q projection via MFMA, bf16 out (32 rows/block) ----------------
__global__ __launch_bounds__(256) void k_proj_q_mfma(
    const float* __restrict__ edge_attr, const ushort* __restrict__ Wb,
    const float* __restrict__ in_proj_b, ushort* __restrict__ Qb) {
  constexpr int IP = 136;
  __shared__ ushort inL[32 * IP];   // 8704 B; reused as outL
  const int t = threadIdx.x;
  const int row0 = blockIdx.x * 32;
  for (int idx = t; idx < 32 * 32; idx += 256) {
    int r = idx >> 5, c = idx & 31;
    float4 v = ((const float4*)(edge_attr + (size_t)(row0 + r) * H))[c];
    ushort4 o; o.x = f2bf(v.x); o.y = f2bf(v.y); o.z = f2bf(v.z); o.w = f2bf(v.w);
    *(ushort4*)(inL + r * IP + c * 4) = o;
  }
  __syncthreads();
  const int w = t >> 6, lane = t & 63, g = lane >> 4, l15 = lane & 15;
  const int rt = w & 1, wr = rt * 16;
  bf16x8 a[4];
#pragma unroll
  for (int kc = 0; kc < 4; kc++)
    a[kc] = *(const bf16x8*)(inL + (wr + l15) * IP + kc * 32 + g * 8);
  __syncthreads();   // inL free -> outL
  const float* bq = in_proj_b;
#pragma unroll
  for (int ci = 0; ci < 4; ci++) {
    int ct = (w >> 1) * 4 + ci;
    f32x4 acc = {0.f, 0.f, 0.f, 0.f};
#pragma unroll
    for (int kc = 0; kc < 4; kc++) {
      bf16x8 bw = *(const bf16x8*)(Wb + WQ_OFF + (size_t)(ct * 16 + l15) * H + kc * 32 + g * 8);
      acc = __builtin_amdgcn_mfma_f32_16x16x32_bf16(a[kc], bw, acc, 0, 0, 0);
    }
    int oc = ct * 16 + l15;
    float bb = bq[oc];
#pragma unroll
    for (int r = 0; r < 4; r++)
      inL[(wr + 4 * g + r) * IP + oc] = f2bf(acc[r] + bb);
  }
  __syncthreads();
  for (int idx = t; idx < 32 * 16; idx += 256) {
    int r = idx >> 4, c = idx & 15;
    *(u16x8*)(Qb + (size_t)(row0 + r) * H + c * 8) = *(const u16x8*)(inL + r * IP + c * 8);
  }
}

// ---------------- K2b: K,V projection via MFMA, bf16 out ----------------
__global__ __launch_bounds__(256) void k_proj_kv_mfma(
    const float* __restrict__ edge_attr, const int* __restrict__ iel,
    const ushort* __restrict__ Wb, const float* __restrict__ in_proj_b,
    ushort* __restrict__ Kb, ushort* __restrict__ Vb) {
  constexpr int IP = 136;
  __shared__ ushort inL[64 * IP];
  __shared__ ushort outL[64 * IP];
  const int t = threadIdx.x;
  const int row0 = blockIdx.x * 64;
  for (int idx = t; idx < 64 * 32; idx += 256) {
    int r = idx >> 5, c = idx & 31;
    int srow = iel[row0 + r];
    float4 v = ((const float4*)(edge_attr + (size_t)srow * H))[c];
    ushort4 o; o.x = f2bf(v.x); o.y = f2bf(v.y); o.z = f2bf(v.z); o.w = f2bf(v.w);
    *(ushort4*)(inL + r * IP + c * 4) = o;
  }
  __syncthreads();
  const int w = t >> 6, lane = t & 63, g = lane >> 4, l15 = lane & 15;
  bf16x8 a[4];
#pragma unroll
  for (int kc = 0; kc < 4; kc++)
    a[kc] = *(const bf16x8*)(inL + (w * 16 + l15) * IP + kc * 32 + g * 8);
#pragma unroll
  for (int pass = 0; pass < 2; pass++) {
    const int woff = pass == 0 ? WK_OFF : WV_OFF;
    const float* bias = in_proj_b + H + pass * H;
    ushort* dstg = pass == 0 ? Kb : Vb;
#pragma unroll
    for (int ct = 0; ct < 8; ct++) {
      f32x4 acc = {0.f, 0.f, 0.f, 0.f};
#pragma unroll
      for (int kc = 0; kc < 4; kc++) {
        bf16x8 bw = *(const bf16x8*)(Wb + woff + (size_t)(ct * 16 + l15) * H + kc * 32 + g * 8);
        acc = __builtin_amdgcn_mfma_f32_16x16x32_bf16(a[kc], bw, acc, 0, 0, 0);
      }
      int oc = ct * 16 + l15;
      float bb = bias[oc];
#pragma unroll
      for (int r = 0; r < 4; r++)
        outL[(w * 16 + 4 * g + r) * IP + oc] = f2bf(acc[r] + bb);
    }
    __syncthreads();
    for (int idx = t; idx < 64 * 16; idx += 256) {
      int r = idx >> 4, c = idx & 15;
      *(u16x8*)(dstg + (size_t)(row0 + r) * H + c * 8) = *(const u16x8*)(outL + r * IP + c * 8);
    }
    __syncthreads();
  }
}

// ---------------- K3: MFMA flash attention (bf16 in/out) ----------------
__global__ __launch_bounds__(256) void k_attn_mfma(
    const ushort* __restrict__ Qb, const ushort* __restrict__ Kb,
    const ushort* __restrict__ Vb, const int* __restrict__ sq,
    const int* __restrict__ sk, const float* __restrict__ in_proj_b,
    ushort* __restrict__ CtxB) {
  constexpr int KP = 40;
  constexpr int QP = 40;
  constexpr int VP = 392;
  constexpr int PP = 40;
  __shared__ ushort Kl[LK * KP];
  __shared__ ushort Ql[LQ * QP];
  __shared__ ushort VTl[HD * VP];
  __shared__ ushort Pl[4 * 16 * PP];

  const int b = blockIdx.x, h = blockIdx.y;
  const int t = threadIdx.x;
  const int q0 = sq[b], lenq = sq[b + 1] - q0;
  const int k0 = sk[b], lenk = sk[b + 1] - k0;
  const int nq = lenq < LQ ? lenq : LQ;
  const int nk = lenk < LK ? lenk : LK;
  const int nkc = (nk + 31) & ~31;
  const int nqt = (nq + 15) >> 4;
  u16x8 z8 = {0, 0, 0, 0, 0, 0, 0, 0};

  // stage Q
  for (int idx = t; idx < nq * 4; idx += 256) {
    int row = idx >> 2, c = idx & 3;
    int src = q0 + row;
    if (lenq > LQ && row == LQ - 1) src = q0 + lenq - 1;
    *(u16x8*)(Ql + row * QP + c * 8) = *(const u16x8*)(Qb + (size_t)src * H + h * HD + c * 8);
  }
  for (int idx = t; idx < (nqt * 16 - nq) * 4; idx += 256) {
    int row = nq + (idx >> 2), c = idx & 3;
    *(u16x8*)(Ql + row * QP + c * 8) = z8;
  }
  // stage K
  for (int idx = t; idx < nk * 4; idx += 256) {
    int row = idx >> 2, c = idx & 3;
    int src = k0 + row;
    if (lenk > LK && row == LK - 1) src = k0 + lenk - 1;
    *(u16x8*)(Kl + row * KP + c * 8) = *(const u16x8*)(Kb + (size_t)src * H + h * HD + c * 8);
  }
  for (int idx = t; idx < (nkc - nk) * 4; idx += 256) {
    int row = nk + (idx >> 2), c = idx & 3;
    *(u16x8*)(Kl + row * KP + c * 8) = z8;
  }
  // stage V transposed
  for (int idx = t; idx < nk * 4; idx += 256) {
    int k = idx >> 2, c = idx & 3;
    int src = k0 + k;
    if (lenk > LK && k == LK - 1) src = k0 + lenk - 1;
    u16x8 v = *(const u16x8*)(Vb + (size_t)src * H + h * HD + c * 8);
#pragma unroll
    for (int j = 0; j < 8; j++) VTl[(c * 8 + j) * VP + k] = v[j];
  }
  for (int idx = t; idx < ((nkc - nk) << 5); idx += 256) {
    int d = idx & 31, k = nk + (idx >> 5);
    VTl[d * VP + k] = 0;
  }
  __syncthreads();

  const int wave = t >> 6, lane = t & 63, g = lane >> 4, l15 = lane & 15;
  ushort* Pw = Pl + wave * 16 * PP;
  const float scale = 0.17677669529663687f;  // 1/sqrt(32)

  for (int qt = wave; qt < nqt; qt += 4) {
    bf16x8 bq = *(const bf16x8*)(Ql + (qt * 16 + l15) * QP + g * 8);
    f32x4 o0 = {0.f, 0.f, 0.f, 0.f}, o1 = {0.f, 0.f, 0.f, 0.f};
    float m = -3.0e38f, s = 0.f;
    for (int kc = 0; kc < nk; kc += 32) {
      bf16x8 a0 = *(const bf16x8*)(Kl + (kc + l15) * KP + g * 8);
      bf16x8 a1 = *(const bf16x8*)(Kl + (kc + 16 + l15) * KP + g * 8);
      f32x4 z = {0.f, 0.f, 0.f, 0.f};
      f32x4 s0 = __builtin_amdgcn_mfma_f32_16x16x32_bf16(a0, bq, z, 0, 0, 0);
      f32x4 s1 = __builtin_amdgcn_mfma_f32_16x16x32_bf16(a1, bq, z, 0, 0, 0);
      float p[8];
#pragma unroll
      for (int r = 0; r < 4; r++) {
        p[r]     = (kc + 4 * g + r < nk)      ? s0[r] * scale : -1e30f;
        p[4 + r] = (kc + 16 + 4 * g + r < nk) ? s1[r] * scale : -1e30f;
      }
      float pm = p[0];
#pragma unroll
      for (int r = 1; r < 8; r++) pm = fmaxf(pm, p[r]);
      pm = fmaxf(pm, __shfl_xor(pm, 16));
      pm = fmaxf(pm, __shfl_xor(pm, 32));
      float mn = fmaxf(m, pm);
      float corr = __expf(m - mn);
      float rs = 0.f;
#pragma unroll
      for (int r = 0; r < 8; r++) { p[r] = __expf(p[r] - mn); rs += p[r]; }
      rs += __shfl_xor(rs, 16);
      rs += __shfl_xor(rs, 32);
      s = s * corr + rs;
      m = mn;
      ushort4 w0; w0.x = f2bf(p[0]); w0.y = f2bf(p[1]); w0.z = f2bf(p[2]); w0.w = f2bf(p[3]);
      ushort4 w1; w1.x = f2bf(p[4]); w1.y = f2bf(p[5]); w1.z = f2bf(p[6]); w1.w = f2bf(p[7]);
      __builtin_amdgcn_sched_barrier(0);
      *(ushort4*)(Pw + l15 * PP + 4 * g) = w0;
      *(ushort4*)(Pw + l15 * PP + 16 + 4 * g) = w1;
      asm volatile("s_waitcnt lgkmcnt(0)" ::: "memory");
      __builtin_amdgcn_sched_barrier(0);
      bf16x8 pb = *(const bf16x8*)(Pw + l15 * PP + 8 * g);
      bf16x8 av0 = *(const bf16x8*)(VTl + l15 * VP + kc + 8 * g);
      bf16x8 av1 = *(const bf16x8*)(VTl + (16 + l15) * VP + kc + 8 * g);
#pragma unroll
      for (int r = 0; r < 4; r++) { o0[r] *= corr; o1[r] *= corr; }
      o0 = __builtin_amdgcn_mfma_f32_16x16x32_bf16(av0, pb, o0, 0, 0, 0);
      o1 = __builtin_amdgcn_mfma_f32_16x16x32_bf16(av1, pb, o1, 0, 0, 0);
    }
    int slot = qt * 16 + l15;
    if (slot < nq) {
      int qi = q0 + slot;
      if (lenq > LQ && slot == LQ - 1) qi = q0 + lenq - 1;
      ushort* outp = CtxB + (size_t)qi * H + h * HD;
      if (nk > 0) {
        float inv = 1.f / s;
        ushort4 v0, v1;
#pragma unroll
        for (int r = 0; r < 4; r++) { ((ushort*)&v0)[r] = f2bf(o0[r] * inv); ((ushort*)&v1)[r] = f2bf(o1[r] * inv); }
        *(ushort4*)(outp + 4 * g) = v0;
        *(ushort4*)(outp + 16 + 4 * g) = v1;
      } else {
        const float* bv = in_proj_b + 2 * H + h * HD;
        ushort4 v0, v1;
#pragma unroll
        for (int r = 0; r < 4; r++) { ((ushort*)&v0)[r] = f2bf(bv[4 * g + r]); ((ushort*)&v1)[r] = f2bf(bv[16 + 4 * g + r]); }
        *(ushort4*)(outp + 4 * g) = v0;
        *(ushort4*)(outp + 16 + 4 * g) = v1;
      }
    }
  }
}

// ---------------- K4: out-proj + residual + FFN via MFMA (32 rows/block) ----------------
__global__ __launch_bounds__(256) void k_out_ffn_mfma(
    const ushort* __restrict__ CtxB, const float* __restrict__ edge_attr,
    const int* __restrict__ sq, const int* __restrict__ eb,
    const ushort* __restrict__ Wb, const float* __restrict__ opb,
    const float* __restrict__ b1, const float* __restrict__ b2,
    float* __restrict__ out) {
  constexpr int IP = 136;  // K=128 pitch
  constexpr int HP = 264;  // K=256 pitch
  __shared__ ushort attB[32 * IP];  // ctx staging, then att bf16
  __shared__ ushort h1L[32 * HP];   // h1 bf16
  const int t = threadIdx.x;
  const int row0 = blockIdx.x * 32;

  // stage ctx rows bf16 (with q-clip source mapping) into attB region
  for (int idx = t; idx < 32 * 16; idx += 256) {
    int r = idx >> 4, c = idx & 15;
    int i = row0 + r;
    int bb = eb[i];
    int qq0 = sq[bb];
    int lenq = sq[bb + 1] - qq0;
    int src = i;
    if (lenq > LQ && (i - qq0) >= LQ - 1) src = qq0 + lenq - 1;
    *(u16x8*)(attB + r * IP + c * 8) = *(const u16x8*)(CtxB + (size_t)src * H + c * 8);
  }
  __syncthreads();

  const int w = t >> 6, lane = t & 63, g = lane >> 4, l15 = lane & 15;
  const int rt = w & 1, wr = rt * 16, ch = w >> 1;   // row-tile, col-half
  bf16x8 ca[4];
#pragma unroll
  for (int kc = 0; kc < 4; kc++)
    ca[kc] = *(const bf16x8*)(attB + (wr + l15) * IP + kc * 32 + g * 8);
  __syncthreads();   // attB free for att writes

  // phase A: att = ctx @ opw^T + opb + edge_attr (4 ct tiles/wave, regs + bf16 LDS)
  float att[4][4];
#pragma unroll
  for (int ci = 0; ci < 4; ci++) {
    int ct = ch * 4 + ci;
    f32x4 acc = {0.f, 0.f, 0.f, 0.f};
#pragma unroll
    for (int kc = 0; kc < 4; kc++) {
      bf16x8 bw = *(const bf16x8*)(Wb + OPW_OFF + (size_t)(ct * 16 + l15) * H + kc * 32 + g * 8);
      acc = __builtin_amdgcn_mfma_f32_16x16x32_bf16(ca[kc], bw, acc, 0, 0, 0);
    }
    int oc = ct * 16 + l15;
    float bo = opb[oc];
#pragma unroll
    for (int r = 0; r < 4; r++) {
      float v = acc[r] + bo + edge_attr[(size_t)(row0 + wr + 4 * g + r) * H + oc];
      att[ci][r] = v;
      attB[(wr + 4 * g + r) * IP + oc] = f2bf(v);
    }
  }
  __syncthreads();

  // phase B: h1 = relu(att @ w1^T + b1) -> bf16 LDS (8 ct tiles/wave)
  bf16x8 aa[4];
#pragma unroll
  for (int kc = 0; kc < 4; kc++)
    aa[kc] = *(const bf16x8*)(attB + (wr + l15) * IP + kc * 32 + g * 8);
#pragma unroll
  for (int ci = 0; ci < 8; ci++) {
    int ct = ch * 8 + ci;
    f32x4 acc = {0.f, 0.f, 0.f, 0.f};
#pragma unroll
    for (int kc = 0; kc < 4; kc++) {
      bf16x8 bw = *(const bf16x8*)(Wb + W1_OFF + (size_t)(ct * 16 + l15) * H + kc * 32 + g * 8);
      acc = __builtin_amdgcn_mfma_f32_16x16x32_bf16(aa[kc], bw, acc, 0, 0, 0);
    }
    int oc = ct * 16 + l15;
    float bb = b1[oc];
#pragma unroll
    for (int r = 0; r < 4; r++)
      h1L[(wr + 4 * g + r) * HP + oc] = f2bf(fmaxf(acc[r] + bb, 0.f));
  }
  __syncthreads();

  // phase C: out = att + h1 @ w2^T + b2 (same 4 ct tiles as phase A -> att regs)
  bf16x8 ha[8];
#pragma unroll
  for (int kc = 0; kc < 8; kc++)
    ha[kc] = *(const bf16x8*)(h1L + (wr + l15) * HP + kc * 32 + g * 8);
#pragma unroll
  for (int ci = 0; ci < 4; ci++) {
    int ct = ch * 4 + ci;
    f32x4 acc = {0.f, 0.f, 0.f, 0.f};
#pragma unroll
    for (int kc = 0; kc < 8; kc++) {
      bf16x8 bw = *(const bf16x8*)(Wb + W2_OFF + (size_t)(ct * 16 + l15) * 2 * H + kc * 32 + g * 8);
      acc = __builtin_amdgcn_mfma_f32_16x16x32_bf16(ha[kc], bw, acc, 0, 0, 0);
    }
    int oc = ct * 16 + l15;
    float bb = b2[oc];
#pragma unroll
    for (int r = 0; r < 4; r++)
      out[(size_t)(row0 + wr + 4 * g + r) * H + oc] = att[ci][r] + acc[r] + bb;
  }
}

extern "C" void kernel_launch(void* const* d_in, const int* in_sizes, int n_in,
                              void* d_out, int out_size, void* d_ws, size_t ws_size,
                              hipStream_t stream) {
  const float* edge_attr = (const float*)d_in[1];
  const int*   iel       = (const int*)d_in[2];
  const int*   ieb       = (const int*)d_in[3];
  const int*   eb        = (const int*)d_in[4];
  const float* in_proj_w = (const float*)d_in[5];
  const float* in_proj_b = (const float*)d_in[6];
  const float* opw       = (const float*)d_in[7];
  const float* opb       = (const float*)d_in[8];
  const float* w1        = (const float*)d_in[9];
  const float* b1        = (const float*)d_in[10];
  const float* w2        = (const float*)d_in[11];
  const float* b2        = (const float*)d_in[12];
  float* out = (float*)d_out;

  char* ws = (char*)d_ws;
  int* sq = (int*)ws;
  int* sk = (int*)(ws + 2048);
  ushort* Qb   = (ushort*)(ws + 4096);            // E*H bf16
  ushort* Kb   = Qb + (size_t)E * H;              // M*H bf16
  ushort* Vb   = Kb + (size_t)M * H;              // M*H bf16
  ushort* CtxB = Vb + (size_t)M * H;              // E*H bf16
  ushort* Wb   = CtxB + (size_t)E * H;            // 131072 bf16 weights

  k_starts_prep<<<dim3(129), dim3(256), 0, stream>>>(eb, ieb, sq, sk, in_proj_w, opw, w1, w2, Wb);
  k_proj_q_mfma<<<dim3(E / 32), dim3(256), 0, stream>>>(edge_attr, Wb, in_proj_b, Qb);
  k_proj_kv_mfma<<<dim3(M / 64), dim3(256), 0, stream>>>(edge_attr, iel, Wb, in_proj_b, Kb, Vb);
  k_attn_mfma<<<dim3(B, NH), dim3(256), 0, stream>>>(Qb, Kb, Vb, sq, sk, in_proj_b, CtxB);
  k_out_ffn_mfma<<<dim3(E / 32), dim3(256), 0, stream>>>(CtxB, edge_attr, sq, eb, Wb, opb, b1, b2, out);
}

// Round 8
// 123.241 us; speedup vs baseline: 3.2946x; 1.0005x over previous
//
#include <hip/hip_runtime.h>
#include <hip/hip_bf16.h>

constexpr int B  = 256;
constexpr int E  = 16384;
constexpr int M  = 65536;
constexpr int H  = 128;
constexpr int NH = 4;
constexpr int HD = 32;
constexpr int LQ = 128;
constexpr int LK = 384;

// bf16 weight buffer offsets (elements)
constexpr int WQ_OFF  = 0;
constexpr int WK_OFF  = 16384;
constexpr int WV_OFF  = 32768;
constexpr int OPW_OFF = 49152;
constexpr int W1_OFF  = 65536;
constexpr int W2_OFF  = 98304;
constexpr int W_TOTAL = 131072;

typedef __attribute__((ext_vector_type(8))) short bf16x8;
typedef __attribute__((ext_vector_type(8))) unsigned short u16x8;
typedef __attribute__((ext_vector_type(4))) float f32x4;

__device__ __forceinline__ ushort f2bf(float x) {
  union { float f; unsigned u; } v; v.f = x;
  unsigned r = (v.u + 0x7FFFu + ((v.u >> 16) & 1u)) >> 16;
  return (ushort)r;
}

// ---------------- K1: starts + bf16 weights + bf16 edge_attr copy ----------------
__global__ __launch_bounds__(256) void k_starts_prep(
    const int* __restrict__ eb, const int* __restrict__ ieb,
    int* __restrict__ sq, int* __restrict__ sk,
    const float* __restrict__ in_proj_w, const float* __restrict__ opw,
    const float* __restrict__ w1, const float* __restrict__ w2,
    const float* __restrict__ edge_attr,
    ushort* __restrict__ Wb, ushort* __restrict__ Eb) {
  const int bx = blockIdx.x, t = threadIdx.x;
  if (bx == 0) {
    for (int i = t; i <= B; i += 256) {
      int lo = 0, hi = E;
      while (lo < hi) { int mid = (lo + hi) >> 1; if (eb[mid] < i) lo = mid + 1; else hi = mid; }
      sq[i] = lo;
      lo = 0; hi = M;
      while (lo < hi) { int mid = (lo + hi) >> 1; if (ieb[mid] < i) lo = mid + 1; else hi = mid; }
      sk[i] = lo;
    }
  } else if (bx <= 128) {
    int i = ((bx - 1) * 256 + t) * 4;
    if (i < W_TOTAL) {
      float4 v;
      if (i < OPW_OFF)      v = *(const float4*)(in_proj_w + i);
      else if (i < W1_OFF)  v = *(const float4*)(opw + (i - OPW_OFF));
      else if (i < W2_OFF)  v = *(const float4*)(w1 + (i - W1_OFF));
      else                  v = *(const float4*)(w2 + (i - W2_OFF));
      ushort4 o; o.x = f2bf(v.x); o.y = f2bf(v.y); o.z = f2bf(v.z); o.w = f2bf(v.w);
      *(ushort4*)(Wb + i) = o;
    }
  } else {
    int i = ((bx - 129) * 256 + t) * 4;   // E*H = 2M elems, 2048 blocks
    float4 v = *(const float4*)(edge_attr + i);
    ushort4 o; o.x = f2bf(v.x); o.y = f2bf(v.y); o.z = f2bf(v.z); o.w = f2bf(v.w);
    *(ushort4*)(Eb + i) = o;
  }
}

// ---------------- K2a: Q projection (swapped MFMA, direct stores) ----------------
__global__ __launch_bounds__(256) void k_proj_q_mfma(
    const ushort* __restrict__ Eb, const ushort* __restrict__ Wb,
    const float* __restrict__ in_proj_b, ushort* __restrict__ Qb) {
  constexpr int IP = 136;
  __shared__ ushort inL[32 * IP];
  const int t = threadIdx.x;
  const int row0 = blockIdx.x * 32;
  for (int idx = t; idx < 32 * 16; idx += 256) {
    int r = idx >> 4, c = idx & 15;
    *(u16x8*)(inL + r * IP + c * 8) = *(const u16x8*)(Eb + (size_t)(row0 + r) * H + c * 8);
  }
  __syncthreads();
  const int w = t >> 6, lane = t & 63, g = lane >> 4, l15 = lane & 15;
  const int wr = (w & 1) * 16, ch = w >> 1;
  bf16x8 a[4];
#pragma unroll
  for (int kc = 0; kc < 4; kc++)
    a[kc] = *(const bf16x8*)(inL + (wr + l15) * IP + kc * 32 + g * 8);
  const int row = row0 + wr + l15;
#pragma unroll
  for (int ci = 0; ci < 4; ci++) {
    int ct = ch * 4 + ci;
    f32x4 acc = {0.f, 0.f, 0.f, 0.f};
#pragma unroll
    for (int kc = 0; kc < 4; kc++) {
      bf16x8 bw = *(const bf16x8*)(Wb + WQ_OFF + (size_t)(ct * 16 + l15) * H + kc * 32 + g * 8);
      acc = __builtin_amdgcn_mfma_f32_16x16x32_bf16(bw, a[kc], acc, 0, 0, 0);
    }
    int oc = ct * 16 + 4 * g;
    float4 bb = *(const float4*)(in_proj_b + oc);
    ushort4 v;
    v.x = f2bf(acc[0] + bb.x); v.y = f2bf(acc[1] + bb.y);
    v.z = f2bf(acc[2] + bb.z); v.w = f2bf(acc[3] + bb.w);
    *(ushort4*)(Qb + (size_t)row * H + oc) = v;
  }
}

// ---------------- K2b: K,V projection (swapped MFMA, fused K|V, direct stores) ----------------
__global__ __launch_bounds__(256) void k_proj_kv_mfma(
    const ushort* __restrict__ Eb, const int* __restrict__ iel,
    const ushort* __restrict__ Wb, const float* __restrict__ in_proj_b,
    ushort* __restrict__ Kb, ushort* __restrict__ Vb) {
  constexpr int IP = 136;
  __shared__ ushort inL[64 * IP];   // 17408 B
  const int t = threadIdx.x;
  const int row0 = blockIdx.x * 64;
  for (int idx = t; idx < 64 * 16; idx += 256) {
    int r = idx >> 4, c = idx & 15;
    int srow = iel[row0 + r];
    *(u16x8*)(inL + r * IP + c * 8) = *(const u16x8*)(Eb + (size_t)srow * H + c * 8);
  }
  __syncthreads();
  const int w = t >> 6, lane = t & 63, g = lane >> 4, l15 = lane & 15;
  bf16x8 a[4];
#pragma unroll
  for (int kc = 0; kc < 4; kc++)
    a[kc] = *(const bf16x8*)(inL + (w * 16 + l15) * IP + kc * 32 + g * 8);
  const int row = row0 + w * 16 + l15;
#pragma unroll
  for (int ct = 0; ct < 16; ct++) {
    const int woff = (ct < 8) ? WK_OFF : WV_OFF;
    const int cc = (ct & 7) * 16;
    f32x4 acc = {0.f, 0.f, 0.f, 0.f};
#pragma unroll
    for (int kc = 0; kc < 4; kc++) {
      bf16x8 bw = *(const bf16x8*)(Wb + woff + (size_t)(cc + l15) * H + kc * 32 + g * 8);
      acc = __builtin_amdgcn_mfma_f32_16x16x32_bf16(bw, a[kc], acc, 0, 0, 0);
    }
    int oc = cc + 4 * g;
    float4 bb = *(const float4*)(in_proj_b + H + ((ct < 8) ? 0 : H) + oc);
    ushort4 v;
    v.x = f2bf(acc[0] + bb.x); v.y = f2bf(acc[1] + bb.y);
    v.z = f2bf(acc[2] + bb.z); v.w = f2bf(acc[3] + bb.w);
    ushort* dstg = (ct < 8) ? Kb : Vb;
    *(ushort4*)(dstg + (size_t)row * H + oc) = v;
  }
}

// ---------------- K3: MFMA flash attention (bf16 in/out) ----------------
__global__ __launch_bounds__(256) void k_attn_mfma(
    const ushort* __restrict__ Qb, const ushort* __restrict__ Kb,
    const ushort* __restrict__ Vb, const int* __restrict__ sq,
    const int* __restrict__ sk, const float* __restrict__ in_proj_b,
    ushort* __restrict__ CtxB) {
  constexpr int KP = 40;
  constexpr int QP = 40;
  constexpr int VP = 392;
  constexpr int PP = 40;
  __shared__ ushort Kl[LK * KP];
  __shared__ ushort Ql[LQ * QP];
  __shared__ ushort VTl[HD * VP];
  __shared__ ushort Pl[4 * 16 * PP];

  const int b = blockIdx.x, h = blockIdx.y;
  const int t = threadIdx.x;
  const int q0 = sq[b], lenq = sq[b + 1] - q0;
  const int k0 = sk[b], lenk = sk[b + 1] - k0;
  const int nq = lenq < LQ ? lenq : LQ;
  const int nk = lenk < LK ? lenk : LK;
  const int nkc = (nk + 31) & ~31;
  const int nqt = (nq + 15) >> 4;
  u16x8 z8 = {0, 0, 0, 0, 0, 0, 0, 0};

  for (int idx = t; idx < nq * 4; idx += 256) {
    int row = idx >> 2, c = idx & 3;
    int src = q0 + row;
    if (lenq > LQ && row == LQ - 1) src = q0 + lenq - 1;
    *(u16x8*)(Ql + row * QP + c * 8) = *(const u16x8*)(Qb + (size_t)src * H + h * HD + c * 8);
  }
  for (int idx = t; idx < (nqt * 16 - nq) * 4; idx += 256) {
    int row = nq + (idx >> 2), c = idx & 3;
    *(u16x8*)(Ql + row * QP + c * 8) = z8;
  }
  for (int idx = t; idx < nk * 4; idx += 256) {
    int row = idx >> 2, c = idx & 3;
    int src = k0 + row;
    if (lenk > LK && row == LK - 1) src = k0 + lenk - 1;
    *(u16x8*)(Kl + row * KP + c * 8) = *(const u16x8*)(Kb + (size_t)src * H + h * HD + c * 8);
  }
  for (int idx = t; idx < (nkc - nk) * 4; idx += 256) {
    int row = nk + (idx >> 2), c = idx & 3;
    *(u16x8*)(Kl + row * KP + c * 8) = z8;
  }
  for (int idx = t; idx < nk * 4; idx += 256) {
    int k = idx >> 2, c = idx & 3;
    int src = k0 + k;
    if (lenk > LK && k == LK - 1) src = k0 + lenk - 1;
    u16x8 v = *(const u16x8*)(Vb + (size_t)src * H + h * HD + c * 8);
#pragma unroll
    for (int j = 0; j < 8; j++) VTl[(c * 8 + j) * VP + k] = v[j];
  }
  for (int idx = t; idx < ((nkc - nk) << 5); idx += 256) {
    int d = idx & 31, k = nk + (idx >> 5);
    VTl[d * VP + k] = 0;
  }
  __syncthreads();

  const int wave = t >> 6, lane = t & 63, g = lane >> 4, l15 = lane & 15;
  ushort* Pw = Pl + wave * 16 * PP;
  const float scale = 0.17677669529663687f;  // 1/sqrt(32)

  for (int qt = wave; qt < nqt; qt += 4) {
    bf16x8 bq = *(const bf16x8*)(Ql + (qt * 16 + l15) * QP + g * 8);
    f32x4 o0 = {0.f, 0.f, 0.f, 0.f}, o1 = {0.f, 0.f, 0.f, 0.f};
    float m = -3.0e38f, s = 0.f;
    for (int kc = 0; kc < nk; kc += 32) {
      bf16x8 a0 = *(const bf16x8*)(Kl + (kc + l15) * KP + g * 8);
      bf16x8 a1 = *(const bf16x8*)(Kl + (kc + 16 + l15) * KP + g * 8);
      f32x4 z = {0.f, 0.f, 0.f, 0.f};
      f32x4 s0 = __builtin_amdgcn_mfma_f32_16x16x32_bf16(a0, bq, z, 0, 0, 0);
      f32x4 s1 = __builtin_amdgcn_mfma_f32_16x16x32_bf16(a1, bq, z, 0, 0, 0);
      float p[8];
#pragma unroll
      for (int r = 0; r < 4; r++) {
        p[r]     = (kc + 4 * g + r < nk)      ? s0[r] * scale : -1e30f;
        p[4 + r] = (kc + 16 + 4 * g + r < nk) ? s1[r] * scale : -1e30f;
      }
      float pm = p[0];
#pragma unroll
      for (int r = 1; r < 8; r++) pm = fmaxf(pm, p[r]);
      pm = fmaxf(pm, __shfl_xor(pm, 16));
      pm = fmaxf(pm, __shfl_xor(pm, 32));
      float mn = fmaxf(m, pm);
      float corr = __expf(m - mn);
      float rs = 0.f;
#pragma unroll
      for (int r = 0; r < 8; r++) { p[r] = __expf(p[r] - mn); rs += p[r]; }
      rs += __shfl_xor(rs, 16);
      rs += __shfl_xor(rs, 32);
      s = s * corr + rs;
      m = mn;
      ushort4 w0; w0.x = f2bf(p[0]); w0.y = f2bf(p[1]); w0.z = f2bf(p[2]); w0.w = f2bf(p[3]);
      ushort4 w1; w1.x = f2bf(p[4]); w1.y = f2bf(p[5]); w1.z = f2bf(p[6]); w1.w = f2bf(p[7]);
      __builtin_amdgcn_sched_barrier(0);
      *(ushort4*)(Pw + l15 * PP + 4 * g) = w0;
      *(ushort4*)(Pw + l15 * PP + 16 + 4 * g) = w1;
      asm volatile("s_waitcnt lgkmcnt(0)" ::: "memory");
      __builtin_amdgcn_sched_barrier(0);
      bf16x8 pb = *(const bf16x8*)(Pw + l15 * PP + 8 * g);
      bf16x8 av0 = *(const bf16x8*)(VTl + l15 * VP + kc + 8 * g);
      bf16x8 av1 = *(const bf16x8*)(VTl + (16 + l15) * VP + kc + 8 * g);
#pragma unroll
      for (int r = 0; r < 4; r++) { o0[r] *= corr; o1[r] *= corr; }
      o0 = __builtin_amdgcn_mfma_f32_16x16x32_bf16(av0, pb, o0, 0, 0, 0);
      o1 = __builtin_amdgcn_mfma_f32_16x16x32_bf16(av1, pb, o1, 0, 0, 0);
    }
    int slot = qt * 16 + l15;
    if (slot < nq) {
      int qi = q0 + slot;
      if (lenq > LQ && slot == LQ - 1) qi = q0 + lenq - 1;
      ushort* outp = CtxB + (size_t)qi * H + h * HD;
      if (nk > 0) {
        float inv = 1.f / s;
        ushort4 v0, v1;
#pragma unroll
        for (int r = 0; r < 4; r++) { ((ushort*)&v0)[r] = f2bf(o0[r] * inv); ((ushort*)&v1)[r] = f2bf(o1[r] * inv); }
        *(ushort4*)(outp + 4 * g) = v0;
        *(ushort4*)(outp + 16 + 4 * g) = v1;
      } else {
        const float* bv = in_proj_b + 2 * H + h * HD;
        ushort4 v0, v1;
#pragma unroll
        for (int r = 0; r < 4; r++) { ((ushort*)&v0)[r] = f2bf(bv[4 * g + r]); ((ushort*)&v1)[r] = f2bf(bv[16 + 4 * g + r]); }
        *(ushort4*)(outp + 4 * g) = v0;
        *(ushort4*)(outp + 16 + 4 * g) = v1;
      }
    }
  }
}

// ---------------- K4: out-proj + residual + FFN (swapped MFMA) ----------------
__global__ __launch_bounds__(256) void k_out_ffn_mfma(
    const ushort* __restrict__ CtxB, const float* __restrict__ edge_attr,
    const int* __restrict__ sq, const int* __restrict__ eb,
    const ushort* __restrict__ Wb, const float* __restrict__ opb,
    const float* __restrict__ b1, const float* __restrict__ b2,
    float* __restrict__ out) {
  constexpr int IP = 136;  // K=128 pitch
  constexpr int HP = 264;  // K=256 pitch
  __shared__ ushort attB[32 * IP];  // ctx staging, then att bf16
  __shared__ ushort h1L[32 * HP];   // h1 bf16
  const int t = threadIdx.x;
  const int row0 = blockIdx.x * 32;

  for (int idx = t; idx < 32 * 16; idx += 256) {
    int r = idx >> 4, c = idx & 15;
    int i = row0 + r;
    int bb = eb[i];
    int qq0 = sq[bb];
    int lenq = sq[bb + 1] - qq0;
    int src = i;
    if (lenq > LQ && (i - qq0) >= LQ - 1) src = qq0 + lenq - 1;
    *(u16x8*)(attB + r * IP + c * 8) = *(const u16x8*)(CtxB + (size_t)src * H + c * 8);
  }
  __syncthreads();

  const int w = t >> 6, lane = t & 63, g = lane >> 4, l15 = lane & 15;
  const int wr = (w & 1) * 16, ch = w >> 1;
  const int row = row0 + wr + l15;
  bf16x8 ca[4];
#pragma unroll
  for (int kc = 0; kc < 4; kc++)
    ca[kc] = *(const bf16x8*)(attB + (wr + l15) * IP + kc * 32 + g * 8);
  __syncthreads();   // attB free for att writes

  // phase A: att = ctx @ opw^T + opb + edge_attr
  float att[4][4];
#pragma unroll
  for (int ci = 0; ci < 4; ci++) {
    int ct = ch * 4 + ci;
    f32x4 acc = {0.f, 0.f, 0.f, 0.f};
#pragma unroll
    for (int kc = 0; kc < 4; kc++) {
      bf16x8 bw = *(const bf16x8*)(Wb + OPW_OFF + (size_t)(ct * 16 + l15) * H + kc * 32 + g * 8);
      acc = __builtin_amdgcn_mfma_f32_16x16x32_bf16(bw, ca[kc], acc, 0, 0, 0);
    }
    int oc = ct * 16 + 4 * g;
    float4 bo = *(const float4*)(opb + oc);
    float4 ea = *(const float4*)(edge_attr + (size_t)row * H + oc);
    ushort4 v;
    att[ci][0] = acc[0] + bo.x + ea.x; v.x = f2bf(att[ci][0]);
    att[ci][1] = acc[1] + bo.y + ea.y; v.y = f2bf(att[ci][1]);
    att[ci][2] = acc[2] + bo.z + ea.z; v.z = f2bf(att[ci][2]);
    att[ci][3] = acc[3] + bo.w + ea.w; v.w = f2bf(att[ci][3]);
    *(ushort4*)(attB + (wr + l15) * IP + oc) = v;
  }
  __syncthreads();

  // phase B: h1 = relu(att @ w1^T + b1)
  bf16x8 aa[4];
#pragma unroll
  for (int kc = 0; kc < 4; kc++)
    aa[kc] = *(const bf16x8*)(attB + (wr + l15) * IP + kc * 32 + g * 8);
#pragma unroll
  for (int ci = 0; ci < 8; ci++) {
    int ct = ch * 8 + ci;
    f32x4 acc = {0.f, 0.f, 0.f, 0.f};
#pragma unroll
    for (int kc = 0; kc < 4; kc++) {
      bf16x8 bw = *(const bf16x8*)(Wb + W1_OFF + (size_t)(ct * 16 + l15) * H + kc * 32 + g * 8);
      acc = __builtin_amdgcn_mfma_f32_16x16x32_bf16(bw, aa[kc], acc, 0, 0, 0);
    }
    int oc = ct * 16 + 4 * g;
    float4 bb = *(const float4*)(b1 + oc);
    ushort4 v;
    v.x = f2bf(fmaxf(acc[0] + bb.x, 0.f)); v.y = f2bf(fmaxf(acc[1] + bb.y, 0.f));
    v.z = f2bf(fmaxf(acc[2] + bb.z, 0.f)); v.w = f2bf(fmaxf(acc[3] + bb.w, 0.f));
    *(ushort4*)(h1L + (wr + l15) * HP + oc) = v;
  }
  __syncthreads();

  // phase C: out = att + h1 @ w2^T + b2
  bf16x8 ha[8];
#pragma unroll
  for (int kc = 0; kc < 8; kc++)
    ha[kc] = *(const bf16x8*)(h1L + (wr + l15) * HP + kc * 32 + g * 8);
#pragma unroll
  for (int ci = 0; ci < 4; ci++) {
    int ct = ch * 4 + ci;
    f32x4 acc = {0.f, 0.f, 0.f, 0.f};
#pragma unroll
    for (int kc = 0; kc < 8; kc++) {
      bf16x8 bw = *(const bf16x8*)(Wb + W2_OFF + (size_t)(ct * 16 + l15) * 2 * H + kc * 32 + g * 8);
      acc = __builtin_amdgcn_mfma_f32_16x16x32_bf16(bw, ha[kc], acc, 0, 0, 0);
    }
    int oc = ct * 16 + 4 * g;
    float4 bb = *(const float4*)(b2 + oc);
    float4 o;
    o.x = att[ci][0] + acc[0] + bb.x;
    o.y = att[ci][1] + acc[1] + bb.y;
    o.z = att[ci][2] + acc[2] + bb.z;
    o.w = att[ci][3] + acc[3] + bb.w;
    *(float4*)(out + (size_t)row * H + oc) = o;
  }
}

extern "C" void kernel_launch(void* const* d_in, const int* in_sizes, int n_in,
                              void* d_out, int out_size, void* d_ws, size_t ws_size,
                              hipStream_t stream) {
  const float* edge_attr = (const float*)d_in[1];
  const int*   iel       = (const int*)d_in[2];
  const int*   ieb       = (const int*)d_in[3];
  const int*   eb        = (const int*)d_in[4];
  const float* in_proj_w = (const float*)d_in[5];
  const float* in_proj_b = (const float*)d_in[6];
  const float* opw       = (const float*)d_in[7];
  const float* opb       = (const float*)d_in[8];
  const float* w1        = (const float*)d_in[9];
  const float* b1        = (const float*)d_in[10];
  const float* w2        = (const float*)d_in[11];
  const float* b2        = (const float*)d_in[12];
  float* out = (float*)d_out;

  char* ws = (char*)d_ws;
  int* sq = (int*)ws;
  int* sk = (int*)(ws + 2048);
  ushort* Qb   = (ushort*)(ws + 4096);            // E*H bf16
  ushort* Kb   = Qb + (size_t)E * H;              // M*H bf16
  ushort* Vb   = Kb + (size_t)M * H;              // M*H bf16
  ushort* CtxB = Vb + (size_t)M * H;              // E*H bf16
  ushort* Wb   = CtxB + (size_t)E * H;            // 131072 bf16 weights
  ushort* Eb   = Wb + W_TOTAL;                    // E*H bf16 edge_attr

  k_starts_prep<<<dim3(2177), dim3(256), 0, stream>>>(eb, ieb, sq, sk, in_proj_w, opw, w1, w2, edge_attr, Wb, Eb);
  k_proj_q_mfma<<<dim3(E / 32), dim3(256), 0, stream>>>(Eb, Wb, in_proj_b, Qb);
  k_proj_kv_mfma<<<dim3(M / 64), dim3(256), 0, stream>>>(Eb, iel, Wb, in_proj_b, Kb, Vb);
  k_attn_mfma<<<dim3(B, NH), dim3(256), 0, stream>>>(Qb, Kb, Vb, sq, sk, in_proj_b, CtxB);
  k_out_ffn_mfma<<<dim3(E / 32), dim3(256), 0, stream>>>(CtxB, edge_attr, sq, eb, Wb, opb, b1, b2, out);
}

// Round 10
// 118.857 us; speedup vs baseline: 3.4161x; 1.0369x over previous
//
#include <hip/hip_runtime.h>
#include <hip/hip_bf16.h>

constexpr int B  = 256;
constexpr int E  = 16384;
constexpr int M  = 65536;
constexpr int H  = 128;
constexpr int NH = 4;
constexpr int HD = 32;
constexpr int LQ = 128;
constexpr int LK = 384;

// bf16 weight buffer offsets (elements)
constexpr int WQ_OFF  = 0;
constexpr int WK_OFF  = 16384;
constexpr int WV_OFF  = 32768;
constexpr int OPW_OFF = 49152;
constexpr int W1_OFF  = 65536;
constexpr int W2_OFF  = 98304;
constexpr int W_TOTAL = 131072;

typedef __attribute__((ext_vector_type(8))) short bf16x8;
typedef __attribute__((ext_vector_type(8))) unsigned short u16x8;
typedef __attribute__((ext_vector_type(4))) float f32x4;

__device__ __forceinline__ ushort f2bf(float x) {
  union { float f; unsigned u; } v; v.f = x;
  unsigned r = (v.u + 0x7FFFu + ((v.u >> 16) & 1u)) >> 16;
  return (ushort)r;
}

// ---------------- K1: starts + bf16 weights + bf16 edge_attr copy ----------------
__global__ __launch_bounds__(256) void k_starts_prep(
    const int* __restrict__ eb, const int* __restrict__ ieb,
    int* __restrict__ sq, int* __restrict__ sk,
    const float* __restrict__ in_proj_w, const float* __restrict__ opw,
    const float* __restrict__ w1, const float* __restrict__ w2,
    const float* __restrict__ edge_attr,
    ushort* __restrict__ Wb, ushort* __restrict__ Eb) {
  const int bx = blockIdx.x, t = threadIdx.x;
  if (bx == 0) {
    for (int i = t; i <= B; i += 256) {
      int lo = 0, hi = E;
      while (lo < hi) { int mid = (lo + hi) >> 1; if (eb[mid] < i) lo = mid + 1; else hi = mid; }
      sq[i] = lo;
      lo = 0; hi = M;
      while (lo < hi) { int mid = (lo + hi) >> 1; if (ieb[mid] < i) lo = mid + 1; else hi = mid; }
      sk[i] = lo;
    }
  } else if (bx <= 128) {
    int i = ((bx - 1) * 256 + t) * 4;
    if (i < W_TOTAL) {
      float4 v;
      if (i < OPW_OFF)      v = *(const float4*)(in_proj_w + i);
      else if (i < W1_OFF)  v = *(const float4*)(opw + (i - OPW_OFF));
      else if (i < W2_OFF)  v = *(const float4*)(w1 + (i - W1_OFF));
      else                  v = *(const float4*)(w2 + (i - W2_OFF));
      ushort4 o; o.x = f2bf(v.x); o.y = f2bf(v.y); o.z = f2bf(v.z); o.w = f2bf(v.w);
      *(ushort4*)(Wb + i) = o;
    }
  } else {
    int i = ((bx - 129) * 256 + t) * 4;   // E*H = 2M elems, 2048 blocks
    float4 v = *(const float4*)(edge_attr + i);
    ushort4 o; o.x = f2bf(v.x); o.y = f2bf(v.y); o.z = f2bf(v.z); o.w = f2bf(v.w);
    *(ushort4*)(Eb + i) = o;
  }
}

// ---------------- K2: merged Q|K|V projection (32-row blocks) ----------------
// grid = E/32 Q-blocks followed by M/32 KV-blocks.
__global__ __launch_bounds__(256) void k_proj_qkv(
    const ushort* __restrict__ Eb, const int* __restrict__ iel,
    const ushort* __restrict__ Wb, const float* __restrict__ in_proj_b,
    ushort* __restrict__ Qb, ushort* __restrict__ Kb, ushort* __restrict__ Vb) {
  constexpr int IP = 136;
  constexpr int NQB = E / 32;
  __shared__ ushort inL[32 * IP];   // 8704 B
  const int t = threadIdx.x;
  const bool qmode = blockIdx.x < NQB;
  const int row0 = (qmode ? blockIdx.x : blockIdx.x - NQB) * 32;

  for (int idx = t; idx < 32 * 16; idx += 256) {
    int r = idx >> 4, c = idx & 15;
    int srow = qmode ? (row0 + r) : iel[row0 + r];
    *(u16x8*)(inL + r * IP + c * 8) = *(const u16x8*)(Eb + (size_t)srow * H + c * 8);
  }
  __syncthreads();

  const int w = t >> 6, lane = t & 63, g = lane >> 4, l15 = lane & 15;
  const int wr = (w & 1) * 16, ch = w >> 1;
  bf16x8 a[4];
#pragma unroll
  for (int kc = 0; kc < 4; kc++)
    a[kc] = *(const bf16x8*)(inL + (wr + l15) * IP + kc * 32 + g * 8);
  const int row = row0 + wr + l15;

  if (qmode) {
#pragma unroll
    for (int ci = 0; ci < 4; ci++) {
      int ct = ch * 4 + ci;
      f32x4 acc = {0.f, 0.f, 0.f, 0.f};
#pragma unroll
      for (int kc = 0; kc < 4; kc++) {
        bf16x8 bw = *(const bf16x8*)(Wb + WQ_OFF + (size_t)(ct * 16 + l15) * H + kc * 32 + g * 8);
        acc = __builtin_amdgcn_mfma_f32_16x16x32_bf16(bw, a[kc], acc, 0, 0, 0);
      }
      int oc = ct * 16 + 4 * g;
      float4 bb = *(const float4*)(in_proj_b + oc);
      ushort4 v;
      v.x = f2bf(acc[0] + bb.x); v.y = f2bf(acc[1] + bb.y);
      v.z = f2bf(acc[2] + bb.z); v.w = f2bf(acc[3] + bb.w);
      *(ushort4*)(Qb + (size_t)row * H + oc) = v;
    }
  } else {
#pragma unroll
    for (int ci = 0; ci < 8; ci++) {
      int ct = ch * 8 + ci;
      const int woff = (ct < 8) ? WK_OFF : WV_OFF;
      const int cc = (ct & 7) * 16;
      f32x4 acc = {0.f, 0.f, 0.f, 0.f};
#pragma unroll
      for (int kc = 0; kc < 4; kc++) {
        bf16x8 bw = *(const bf16x8*)(Wb + woff + (size_t)(cc + l15) * H + kc * 32 + g * 8);
        acc = __builtin_amdgcn_mfma_f32_16x16x32_bf16(bw, a[kc], acc, 0, 0, 0);
      }
      int oc = cc + 4 * g;
      float4 bb = *(const float4*)(in_proj_b + H + ((ct < 8) ? 0 : H) + oc);
      ushort4 v;
      v.x = f2bf(acc[0] + bb.x); v.y = f2bf(acc[1] + bb.y);
      v.z = f2bf(acc[2] + bb.z); v.w = f2bf(acc[3] + bb.w);
      ushort* dstg = (ct < 8) ? Kb : Vb;
      *(ushort4*)(dstg + (size_t)row * H + oc) = v;
    }
  }
}

// ---------------- K3: MFMA flash attention (bf16 in/out) ----------------
__global__ __launch_bounds__(256) void k_attn_mfma(
    const ushort* __restrict__ Qb, const ushort* __restrict__ Kb,
    const ushort* __restrict__ Vb, const int* __restrict__ sq,
    const int* __restrict__ sk, const float* __restrict__ in_proj_b,
    ushort* __restrict__ CtxB) {
  constexpr int KP = 40;
  constexpr int QP = 40;
  constexpr int VP = 392;
  constexpr int PP = 40;
  __shared__ ushort Kl[LK * KP];
  __shared__ ushort Ql[LQ * QP];
  __shared__ ushort VTl[HD * VP];
  __shared__ ushort Pl[4 * 16 * PP];

  const int b = blockIdx.x, h = blockIdx.y;
  const int t = threadIdx.x;
  const int q0 = sq[b], lenq = sq[b + 1] - q0;
  const int k0 = sk[b], lenk = sk[b + 1] - k0;
  const int nq = lenq < LQ ? lenq : LQ;
  const int nk = lenk < LK ? lenk : LK;
  const int nkc = (nk + 31) & ~31;
  const int nqt = (nq + 15) >> 4;
  u16x8 z8 = {0, 0, 0, 0, 0, 0, 0, 0};

  for (int idx = t; idx < nq * 4; idx += 256) {
    int row = idx >> 2, c = idx & 3;
    int src = q0 + row;
    if (lenq > LQ && row == LQ - 1) src = q0 + lenq - 1;
    *(u16x8*)(Ql + row * QP + c * 8) = *(const u16x8*)(Qb + (size_t)src * H + h * HD + c * 8);
  }
  for (int idx = t; idx < (nqt * 16 - nq) * 4; idx += 256) {
    int row = nq + (idx >> 2), c = idx & 3;
    *(u16x8*)(Ql + row * QP + c * 8) = z8;
  }
  for (int idx = t; idx < nk * 4; idx += 256) {
    int row = idx >> 2, c = idx & 3;
    int src = k0 + row;
    if (lenk > LK && row == LK - 1) src = k0 + lenk - 1;
    *(u16x8*)(Kl + row * KP + c * 8) = *(const u16x8*)(Kb + (size_t)src * H + h * HD + c * 8);
  }
  for (int idx = t; idx < (nkc - nk) * 4; idx += 256) {
    int row = nk + (idx >> 2), c = idx & 3;
    *(u16x8*)(Kl + row * KP + c * 8) = z8;
  }
  for (int idx = t; idx < nk * 4; idx += 256) {
    int k = idx >> 2, c = idx & 3;
    int src = k0 + k;
    if (lenk > LK && k == LK - 1) src = k0 + lenk - 1;
    u16x8 v = *(const u16x8*)(Vb + (size_t)src * H + h * HD + c * 8);
#pragma unroll
    for (int j = 0; j < 8; j++) VTl[(c * 8 + j) * VP + k] = v[j];
  }
  for (int idx = t; idx < ((nkc - nk) << 5); idx += 256) {
    int d = idx & 31, k = nk + (idx >> 5);
    VTl[d * VP + k] = 0;
  }
  __syncthreads();

  const int wave = t >> 6, lane = t & 63, g = lane >> 4, l15 = lane & 15;
  ushort* Pw = Pl + wave * 16 * PP;
  const float scale = 0.17677669529663687f;  // 1/sqrt(32)

  for (int qt = wave; qt < nqt; qt += 4) {
    bf16x8 bq = *(const bf16x8*)(Ql + (qt * 16 + l15) * QP + g * 8);
    f32x4 o0 = {0.f, 0.f, 0.f, 0.f}, o1 = {0.f, 0.f, 0.f, 0.f};
    float m = -3.0e38f, s = 0.f;
    for (int kc = 0; kc < nk; kc += 32) {
      bf16x8 a0 = *(const bf16x8*)(Kl + (kc + l15) * KP + g * 8);
      bf16x8 a1 = *(const bf16x8*)(Kl + (kc + 16 + l15) * KP + g * 8);
      f32x4 z = {0.f, 0.f, 0.f, 0.f};
      f32x4 s0 = __builtin_amdgcn_mfma_f32_16x16x32_bf16(a0, bq, z, 0, 0, 0);
      f32x4 s1 = __builtin_amdgcn_mfma_f32_16x16x32_bf16(a1, bq, z, 0, 0, 0);
      float p[8];
#pragma unroll
      for (int r = 0; r < 4; r++) {
        p[r]     = (kc + 4 * g + r < nk)      ? s0[r] * scale : -1e30f;
        p[4 + r] = (kc + 16 + 4 * g + r < nk) ? s1[r] * scale : -1e30f;
      }
      float pm = p[0];
#pragma unroll
      for (int r = 1; r < 8; r++) pm = fmaxf(pm, p[r]);
      pm = fmaxf(pm, __shfl_xor(pm, 16));
      pm = fmaxf(pm, __shfl_xor(pm, 32));
      float mn = fmaxf(m, pm);
      float corr = __expf(m - mn);
      float rs = 0.f;
#pragma unroll
      for (int r = 0; r < 8; r++) { p[r] = __expf(p[r] - mn); rs += p[r]; }
      rs += __shfl_xor(rs, 16);
      rs += __shfl_xor(rs, 32);
      s = s * corr + rs;
      m = mn;
      ushort4 w0; w0.x = f2bf(p[0]); w0.y = f2bf(p[1]); w0.z = f2bf(p[2]); w0.w = f2bf(p[3]);
      ushort4 w1; w1.x = f2bf(p[4]); w1.y = f2bf(p[5]); w1.z = f2bf(p[6]); w1.w = f2bf(p[7]);
      __builtin_amdgcn_sched_barrier(0);
      *(ushort4*)(Pw + l15 * PP + 4 * g) = w0;
      *(ushort4*)(Pw + l15 * PP + 16 + 4 * g) = w1;
      asm volatile("s_waitcnt lgkmcnt(0)" ::: "memory");
      __builtin_amdgcn_sched_barrier(0);
      bf16x8 pb = *(const bf16x8*)(Pw + l15 * PP + 8 * g);
      bf16x8 av0 = *(const bf16x8*)(VTl + l15 * VP + kc + 8 * g);
      bf16x8 av1 = *(const bf16x8*)(VTl + (16 + l15) * VP + kc + 8 * g);
#pragma unroll
      for (int r = 0; r < 4; r++) { o0[r] *= corr; o1[r] *= corr; }
      o0 = __builtin_amdgcn_mfma_f32_16x16x32_bf16(av0, pb, o0, 0, 0, 0);
      o1 = __builtin_amdgcn_mfma_f32_16x16x32_bf16(av1, pb, o1, 0, 0, 0);
    }
    int slot = qt * 16 + l15;
    if (slot < nq) {
      int qi = q0 + slot;
      if (lenq > LQ && slot == LQ - 1) qi = q0 + lenq - 1;
      ushort* outp = CtxB + (size_t)qi * H + h * HD;
      if (nk > 0) {
        float inv = 1.f / s;
        ushort4 v0, v1;
#pragma unroll
        for (int r = 0; r < 4; r++) { ((ushort*)&v0)[r] = f2bf(o0[r] * inv); ((ushort*)&v1)[r] = f2bf(o1[r] * inv); }
        *(ushort4*)(outp + 4 * g) = v0;
        *(ushort4*)(outp + 16 + 4 * g) = v1;
      } else {
        const float* bv = in_proj_b + 2 * H + h * HD;
        ushort4 v0, v1;
#pragma unroll
        for (int r = 0; r < 4; r++) { ((ushort*)&v0)[r] = f2bf(bv[4 * g + r]); ((ushort*)&v1)[r] = f2bf(bv[16 + 4 * g + r]); }
        *(ushort4*)(outp + 4 * g) = v0;
        *(ushort4*)(outp + 16 + 4 * g) = v1;
      }
    }
  }
}

// ---------------- K4: out-proj + residual + FFN (16-row blocks) ----------------
__global__ __launch_bounds__(256) void k_out_ffn_mfma(
    const ushort* __restrict__ CtxB, const float* __restrict__ edge_attr,
    const int* __restrict__ sq, const int* __restrict__ eb,
    const ushort* __restrict__ Wb, const float* __restrict__ opb,
    const float* __restrict__ b1, const float* __restrict__ b2,
    float* __restrict__ out) {
  constexpr int IP = 136;  // K=128 pitch
  constexpr int HP = 264;  // K=256 pitch
  __shared__ ushort attB[16 * IP];  // ctx staging, then att bf16
  __shared__ ushort h1L[16 * HP];   // h1 bf16
  const int t = threadIdx.x;
  const int row0 = blockIdx.x * 16;

  for (int idx = t; idx < 16 * 16; idx += 256) {
    int r = idx >> 4, c = idx & 15;
    int i = row0 + r;
    int bb = eb[i];
    int qq0 = sq[bb];
    int lenq = sq[bb + 1] - qq0;
    int src = i;
    if (lenq > LQ && (i - qq0) >= LQ - 1) src = qq0 + lenq - 1;
    *(u16x8*)(attB + r * IP + c * 8) = *(const u16x8*)(CtxB + (size_t)src * H + c * 8);
  }
  __syncthreads();

  const int w = t >> 6, lane = t & 63, g = lane >> 4, l15 = lane & 15;
  const int row = row0 + l15;
  bf16x8 ca[4];
#pragma unroll
  for (int kc = 0; kc < 4; kc++)
    ca[kc] = *(const bf16x8*)(attB + l15 * IP + kc * 32 + g * 8);
  __syncthreads();   // attB free for att writes

  // phase A: att = ctx @ opw^T + opb + edge_attr  (2 ct tiles per wave)
  float att[2][4];
#pragma unroll
  for (int ci = 0; ci < 2; ci++) {
    int ct = w * 2 + ci;
    f32x4 acc = {0.f, 0.f, 0.f, 0.f};
#pragma unroll
    for (int kc = 0; kc < 4; kc++) {
      bf16x8 bw = *(const bf16x8*)(Wb + OPW_OFF + (size_t)(ct * 16 + l15) * H + kc * 32 + g * 8);
      acc = __builtin_amdgcn_mfma_f32_16x16x32_bf16(bw, ca[kc], acc, 0, 0, 0);
    }
    int oc = ct * 16 + 4 * g;
    float4 bo = *(const float4*)(opb + oc);
    float4 ea = *(const float4*)(edge_attr + (size_t)row * H + oc);
    ushort4 v;
    att[ci][0] = acc[0] + bo.x + ea.x; v.x = f2bf(att[ci][0]);
    att[ci][1] = acc[1] + bo.y + ea.y; v.y = f2bf(att[ci][1]);
    att[ci][2] = acc[2] + bo.z + ea.z; v.z = f2bf(att[ci][2]);
    att[ci][3] = acc[3] + bo.w + ea.w; v.w = f2bf(att[ci][3]);
    *(ushort4*)(attB + l15 * IP + oc) = v;
  }
  __syncthreads();

  // phase B: h1 = relu(att @ w1^T + b1)  (4 ct tiles per wave)
  bf16x8 aa[4];
#pragma unroll
  for (int kc = 0; kc < 4; kc++)
    aa[kc] = *(const bf16x8*)(attB + l15 * IP + kc * 32 + g * 8);
#pragma unroll
  for (int ci = 0; ci < 4; ci++) {
    int ct = w * 4 + ci;
    f32x4 acc = {0.f, 0.f, 0.f, 0.f};
#pragma unroll
    for (int kc = 0; kc < 4; kc++) {
      bf16x8 bw = *(const bf16x8*)(Wb + W1_OFF + (size_t)(ct * 16 + l15) * H + kc * 32 + g * 8);
      acc = __builtin_amdgcn_mfma_f32_16x16x32_bf16(bw, aa[kc], acc, 0, 0, 0);
    }
    int oc = ct * 16 + 4 * g;
    float4 bb = *(const float4*)(b1 + oc);
    ushort4 v;
    v.x = f2bf(fmaxf(acc[0] + bb.x, 0.f)); v.y = f2bf(fmaxf(acc[1] + bb.y, 0.f));
    v.z = f2bf(fmaxf(acc[2] + bb.z, 0.f)); v.w = f2bf(fmaxf(acc[3] + bb.w, 0.f));
    *(ushort4*)(h1L + l15 * HP + oc) = v;
  }
  __syncthreads();

  // phase C: out = att + h1 @ w2^T + b2  (same 2 ct tiles as phase A)
  bf16x8 ha[8];
#pragma unroll
  for (int kc = 0; kc < 8; kc++)
    ha[kc] = *(const bf16x8*)(h1L + l15 * HP + kc * 32 + g * 8);
#pragma unroll
  for (int ci = 0; ci < 2; ci++) {
    int ct = w * 2 + ci;
    f32x4 acc = {0.f, 0.f, 0.f, 0.f};
#pragma unroll
    for (int kc = 0; kc < 8; kc++) {
      bf16x8 bw = *(const bf16x8*)(Wb + W2_OFF + (size_t)(ct * 16 + l15) * 2 * H + kc * 32 + g * 8);
      acc = __builtin_amdgcn_mfma_f32_16x16x32_bf16(bw, ha[kc], acc, 0, 0, 0);
    }
    int oc = ct * 16 + 4 * g;
    float4 bb = *(const float4*)(b2 + oc);
    float4 o;
    o.x = att[ci][0] + acc[0] + bb.x;
    o.y = att[ci][1] + acc[1] + bb.y;
    o.z = att[ci][2] + acc[2] + bb.z;
    o.w = att[ci][3] + acc[3] + bb.w;
    *(float4*)(out + (size_t)row * H + oc) = o;
  }
}

extern "C" void kernel_launch(void* const* d_in, const int* in_sizes, int n_in,
                              void* d_out, int out_size, void* d_ws, size_t ws_size,
                              hipStream_t stream) {
  const float* edge_attr = (const float*)d_in[1];
  const int*   iel       = (const int*)d_in[2];
  const int*   ieb       = (const int*)d_in[3];
  const int*   eb        = (const int*)d_in[4];
  const float* in_proj_w = (const float*)d_in[5];
  const float* in_proj_b = (const float*)d_in[6];
  const float* opw       = (const float*)d_in[7];
  const float* opb       = (const float*)d_in[8];
  const float* w1        = (const float*)d_in[9];
  const float* b1        = (const float*)d_in[10];
  const float* w2        = (const float*)d_in[11];
  const float* b2        = (const float*)d_in[12];
  float* out = (float*)d_out;

  char* ws = (char*)d_ws;
  int* sq = (int*)ws;
  int* sk = (int*)(ws + 2048);
  ushort* Qb   = (ushort*)(ws + 4096);            // E*H bf16
  ushort* Kb   = Qb + (size_t)E * H;              // M*H bf16
  ushort* Vb   = Kb + (size_t)M * H;              // M*H bf16
  ushort* CtxB = Vb + (size_t)M * H;              // E*H bf16
  ushort* Wb   = CtxB + (size_t)E * H;            // 131072 bf16 weights
  ushort* Eb   = Wb + W_TOTAL;                    // E*H bf16 edge_attr

  k_starts_prep<<<dim3(2177), dim3(256), 0, stream>>>(eb, ieb, sq, sk, in_proj_w, opw, w1, w2, edge_attr, Wb, Eb);
  k_proj_qkv<<<dim3(E / 32 + M / 32), dim3(256), 0, stream>>>(Eb, iel, Wb, in_proj_b, Qb, Kb, Vb);
  k_attn_mfma<<<dim3(B, NH), dim3(256), 0, stream>>>(Qb, Kb, Vb, sq, sk, in_proj_b, CtxB);
  k_out_ffn_mfma<<<dim3(E / 16), dim3(256), 0, stream>>>(CtxB, edge_attr, sq, eb, Wb, opb, b1, b2, out);
}

// Round 11
// 94.275 us; speedup vs baseline: 4.3068x; 1.2608x over previous
//
#include <hip/hip_runtime.h>
#include <hip/hip_bf16.h>

constexpr int B  = 256;
constexpr int E  = 16384;
constexpr int M  = 65536;
constexpr int H  = 128;
constexpr int NH = 4;
constexpr int HD = 32;
constexpr int LQ = 128;
constexpr int LK = 384;

// bf16 weight buffer offsets (elements)
constexpr int WQ_OFF  = 0;
constexpr int WK_OFF  = 16384;
constexpr int WV_OFF  = 32768;
constexpr int OPW_OFF = 49152;
constexpr int W1_OFF  = 65536;
constexpr int W2_OFF  = 98304;
constexpr int W_TOTAL = 131072;

typedef __attribute__((ext_vector_type(8))) short bf16x8;
typedef __attribute__((ext_vector_type(8))) unsigned short u16x8;
typedef __attribute__((ext_vector_type(4))) float f32x4;

__device__ __forceinline__ ushort f2bf(float x) {
  union { float f; unsigned u; } v; v.f = x;
  unsigned r = (v.u + 0x7FFFu + ((v.u >> 16) & 1u)) >> 16;
  return (ushort)r;
}

// ---------------- K1: starts + bf16 weights + bf16 edge_attr copy ----------------
__global__ __launch_bounds__(256) void k_starts_prep(
    const int* __restrict__ eb, const int* __restrict__ ieb,
    int* __restrict__ sq, int* __restrict__ sk,
    const float* __restrict__ in_proj_w, const float* __restrict__ opw,
    const float* __restrict__ w1, const float* __restrict__ w2,
    const float* __restrict__ edge_attr,
    ushort* __restrict__ Wb, ushort* __restrict__ Eb) {
  const int bx = blockIdx.x, t = threadIdx.x;
  if (bx == 0) {
    for (int i = t; i <= B; i += 256) {
      int lo = 0, hi = E;
      while (lo < hi) { int mid = (lo + hi) >> 1; if (eb[mid] < i) lo = mid + 1; else hi = mid; }
      sq[i] = lo;
      lo = 0; hi = M;
      while (lo < hi) { int mid = (lo + hi) >> 1; if (ieb[mid] < i) lo = mid + 1; else hi = mid; }
      sk[i] = lo;
    }
  } else if (bx <= 128) {
    int i = ((bx - 1) * 256 + t) * 4;
    if (i < W_TOTAL) {
      float4 v;
      if (i < OPW_OFF)      v = *(const float4*)(in_proj_w + i);
      else if (i < W1_OFF)  v = *(const float4*)(opw + (i - OPW_OFF));
      else if (i < W2_OFF)  v = *(const float4*)(w1 + (i - W1_OFF));
      else                  v = *(const float4*)(w2 + (i - W2_OFF));
      ushort4 o; o.x = f2bf(v.x); o.y = f2bf(v.y); o.z = f2bf(v.z); o.w = f2bf(v.w);
      *(ushort4*)(Wb + i) = o;
    }
  } else {
    int i = ((bx - 129) * 256 + t) * 4;   // E*H = 2M elems, 2048 blocks
    float4 v = *(const float4*)(edge_attr + i);
    ushort4 o; o.x = f2bf(v.x); o.y = f2bf(v.y); o.z = f2bf(v.z); o.w = f2bf(v.w);
    *(ushort4*)(Eb + i) = o;
  }
}

// ---------------- K2: fused QKV-projection + flash attention ----------------
// grid (B, NH), 256 threads = 4 waves. Per block: project this head's 32-ch
// slice of Q/K/V straight into LDS (mfma(A=weights, B=rows): D col=row,
// reg=channel), then flash-attention as before.
__global__ __launch_bounds__(256) void k_attn_fused(
    const ushort* __restrict__ Eb, const int* __restrict__ iel,
    const ushort* __restrict__ Wb, const float* __restrict__ in_proj_b,
    const int* __restrict__ sq, const int* __restrict__ sk,
    ushort* __restrict__ CtxB) {
  constexpr int KP = 40;
  constexpr int QP = 40;
  constexpr int VP = 392;
  constexpr int PP = 40;
  __shared__ ushort Kl[LK * KP];
  __shared__ ushort Ql[LQ * QP];
  __shared__ ushort VTl[HD * VP];
  __shared__ ushort Pl[4 * 16 * PP];

  const int b = blockIdx.x, h = blockIdx.y;
  const int t = threadIdx.x;
  const int q0 = sq[b], lenq = sq[b + 1] - q0;
  const int k0 = sk[b], lenk = sk[b + 1] - k0;
  const int nq = lenq < LQ ? lenq : LQ;
  const int nk = lenk < LK ? lenk : LK;
  const int nkc = (nk + 31) & ~31;
  const int nqt = (nq + 15) >> 4;
  const int nkt = nkc >> 4;

  const int wave = t >> 6, lane = t & 63, g = lane >> 4, l15 = lane & 15;
  const int chb = h * HD;               // head channel base (32 ch)
  const ushort4 z4 = {0, 0, 0, 0};

  // ---- Q projection: per wave, qt tiles ----
  {
    bf16x8 wf[2][4];
#pragma unroll
    for (int ct = 0; ct < 2; ct++)
#pragma unroll
      for (int kc = 0; kc < 4; kc++)
        wf[ct][kc] = *(const bf16x8*)(Wb + WQ_OFF + (size_t)(chb + ct * 16 + l15) * H + kc * 32 + g * 8);
    for (int qt = wave; qt < nqt; qt += 4) {
      int slot = qt * 16 + l15;
      bool valid = slot < nq;
      int src = q0 + slot;
      if (lenq > LQ && slot == LQ - 1) src = q0 + lenq - 1;
      if (!valid) src = q0;
      bf16x8 rb[4];
#pragma unroll
      for (int kc = 0; kc < 4; kc++)
        rb[kc] = *(const bf16x8*)(Eb + (size_t)src * H + kc * 32 + g * 8);
#pragma unroll
      for (int ct = 0; ct < 2; ct++) {
        f32x4 acc = {0.f, 0.f, 0.f, 0.f};
#pragma unroll
        for (int kc = 0; kc < 4; kc++)
          acc = __builtin_amdgcn_mfma_f32_16x16x32_bf16(wf[ct][kc], rb[kc], acc, 0, 0, 0);
        ushort4 v = z4;
        if (valid) {
          float4 bb = *(const float4*)(in_proj_b + chb + ct * 16 + 4 * g);
          v.x = f2bf(acc[0] + bb.x); v.y = f2bf(acc[1] + bb.y);
          v.z = f2bf(acc[2] + bb.z); v.w = f2bf(acc[3] + bb.w);
        }
        *(ushort4*)(Ql + (qt * 16 + l15) * QP + ct * 16 + 4 * g) = v;
      }
    }
  }

  // ---- K,V projection: per wave, kt tiles (shared row gather) ----
  {
    bf16x8 wkf[2][4], wvf[2][4];
#pragma unroll
    for (int ct = 0; ct < 2; ct++)
#pragma unroll
      for (int kc = 0; kc < 4; kc++) {
        wkf[ct][kc] = *(const bf16x8*)(Wb + WK_OFF + (size_t)(chb + ct * 16 + l15) * H + kc * 32 + g * 8);
        wvf[ct][kc] = *(const bf16x8*)(Wb + WV_OFF + (size_t)(chb + ct * 16 + l15) * H + kc * 32 + g * 8);
      }
    for (int kt = wave; kt < nkt; kt += 4) {
      int slot = kt * 16 + l15;
      bool valid = slot < nk;
      int src = 0;
      if (valid) {
        int kj = k0 + slot;
        if (lenk > LK && slot == LK - 1) kj = k0 + lenk - 1;
        src = iel[kj];
      }
      bf16x8 rb[4];
#pragma unroll
      for (int kc = 0; kc < 4; kc++)
        rb[kc] = *(const bf16x8*)(Eb + (size_t)src * H + kc * 32 + g * 8);
      // K -> Kl row-major
#pragma unroll
      for (int ct = 0; ct < 2; ct++) {
        f32x4 acc = {0.f, 0.f, 0.f, 0.f};
#pragma unroll
        for (int kc = 0; kc < 4; kc++)
          acc = __builtin_amdgcn_mfma_f32_16x16x32_bf16(wkf[ct][kc], rb[kc], acc, 0, 0, 0);
        ushort4 v = z4;
        if (valid) {
          float4 bb = *(const float4*)(in_proj_b + H + chb + ct * 16 + 4 * g);
          v.x = f2bf(acc[0] + bb.x); v.y = f2bf(acc[1] + bb.y);
          v.z = f2bf(acc[2] + bb.z); v.w = f2bf(acc[3] + bb.w);
        }
        *(ushort4*)(Kl + (kt * 16 + l15) * KP + ct * 16 + 4 * g) = v;
      }
      // V -> VTl transposed (channel rows)
#pragma unroll
      for (int ct = 0; ct < 2; ct++) {
        f32x4 acc = {0.f, 0.f, 0.f, 0.f};
#pragma unroll
        for (int kc = 0; kc < 4; kc++)
          acc = __builtin_amdgcn_mfma_f32_16x16x32_bf16(wvf[ct][kc], rb[kc], acc, 0, 0, 0);
        if (valid) {
          float4 bb = *(const float4*)(in_proj_b + 2 * H + chb + ct * 16 + 4 * g);
          VTl[(ct * 16 + 4 * g + 0) * VP + kt * 16 + l15] = f2bf(acc[0] + bb.x);
          VTl[(ct * 16 + 4 * g + 1) * VP + kt * 16 + l15] = f2bf(acc[1] + bb.y);
          VTl[(ct * 16 + 4 * g + 2) * VP + kt * 16 + l15] = f2bf(acc[2] + bb.z);
          VTl[(ct * 16 + 4 * g + 3) * VP + kt * 16 + l15] = f2bf(acc[3] + bb.w);
        } else {
#pragma unroll
          for (int r = 0; r < 4; r++)
            VTl[(ct * 16 + 4 * g + r) * VP + kt * 16 + l15] = 0;
        }
      }
    }
  }
  __syncthreads();

  // ---- flash attention ----
  ushort* Pw = Pl + wave * 16 * PP;
  const float scale = 0.17677669529663687f;  // 1/sqrt(32)

  for (int qt = wave; qt < nqt; qt += 4) {
    bf16x8 bq = *(const bf16x8*)(Ql + (qt * 16 + l15) * QP + g * 8);
    f32x4 o0 = {0.f, 0.f, 0.f, 0.f}, o1 = {0.f, 0.f, 0.f, 0.f};
    float m = -3.0e38f, s = 0.f;
    for (int kc = 0; kc < nk; kc += 32) {
      bf16x8 a0 = *(const bf16x8*)(Kl + (kc + l15) * KP + g * 8);
      bf16x8 a1 = *(const bf16x8*)(Kl + (kc + 16 + l15) * KP + g * 8);
      f32x4 z = {0.f, 0.f, 0.f, 0.f};
      f32x4 s0 = __builtin_amdgcn_mfma_f32_16x16x32_bf16(a0, bq, z, 0, 0, 0);
      f32x4 s1 = __builtin_amdgcn_mfma_f32_16x16x32_bf16(a1, bq, z, 0, 0, 0);
      float p[8];
#pragma unroll
      for (int r = 0; r < 4; r++) {
        p[r]     = (kc + 4 * g + r < nk)      ? s0[r] * scale : -1e30f;
        p[4 + r] = (kc + 16 + 4 * g + r < nk) ? s1[r] * scale : -1e30f;
      }
      float pm = p[0];
#pragma unroll
      for (int r = 1; r < 8; r++) pm = fmaxf(pm, p[r]);
      pm = fmaxf(pm, __shfl_xor(pm, 16));
      pm = fmaxf(pm, __shfl_xor(pm, 32));
      float mn = fmaxf(m, pm);
      float corr = __expf(m - mn);
      float rs = 0.f;
#pragma unroll
      for (int r = 0; r < 8; r++) { p[r] = __expf(p[r] - mn); rs += p[r]; }
      rs += __shfl_xor(rs, 16);
      rs += __shfl_xor(rs, 32);
      s = s * corr + rs;
      m = mn;
      ushort4 w0; w0.x = f2bf(p[0]); w0.y = f2bf(p[1]); w0.z = f2bf(p[2]); w0.w = f2bf(p[3]);
      ushort4 w1; w1.x = f2bf(p[4]); w1.y = f2bf(p[5]); w1.z = f2bf(p[6]); w1.w = f2bf(p[7]);
      __builtin_amdgcn_sched_barrier(0);
      *(ushort4*)(Pw + l15 * PP + 4 * g) = w0;
      *(ushort4*)(Pw + l15 * PP + 16 + 4 * g) = w1;
      asm volatile("s_waitcnt lgkmcnt(0)" ::: "memory");
      __builtin_amdgcn_sched_barrier(0);
      bf16x8 pb = *(const bf16x8*)(Pw + l15 * PP + 8 * g);
      bf16x8 av0 = *(const bf16x8*)(VTl + l15 * VP + kc + 8 * g);
      bf16x8 av1 = *(const bf16x8*)(VTl + (16 + l15) * VP + kc + 8 * g);
#pragma unroll
      for (int r = 0; r < 4; r++) { o0[r] *= corr; o1[r] *= corr; }
      o0 = __builtin_amdgcn_mfma_f32_16x16x32_bf16(av0, pb, o0, 0, 0, 0);
      o1 = __builtin_amdgcn_mfma_f32_16x16x32_bf16(av1, pb, o1, 0, 0, 0);
    }
    int slot = qt * 16 + l15;
    if (slot < nq) {
      int qi = q0 + slot;
      if (lenq > LQ && slot == LQ - 1) qi = q0 + lenq - 1;
      ushort* outp = CtxB + (size_t)qi * H + chb;
      if (nk > 0) {
        float inv = 1.f / s;
        ushort4 v0, v1;
#pragma unroll
        for (int r = 0; r < 4; r++) { ((ushort*)&v0)[r] = f2bf(o0[r] * inv); ((ushort*)&v1)[r] = f2bf(o1[r] * inv); }
        *(ushort4*)(outp + 4 * g) = v0;
        *(ushort4*)(outp + 16 + 4 * g) = v1;
      } else {
        const float* bv = in_proj_b + 2 * H + chb;
        ushort4 v0, v1;
#pragma unroll
        for (int r = 0; r < 4; r++) { ((ushort*)&v0)[r] = f2bf(bv[4 * g + r]); ((ushort*)&v1)[r] = f2bf(bv[16 + 4 * g + r]); }
        *(ushort4*)(outp + 4 * g) = v0;
        *(ushort4*)(outp + 16 + 4 * g) = v1;
      }
    }
  }
}

// ---------------- K3: out-proj + residual + FFN (16-row blocks) ----------------
__global__ __launch_bounds__(256) void k_out_ffn_mfma(
    const ushort* __restrict__ CtxB, const float* __restrict__ edge_attr,
    const int* __restrict__ sq, const int* __restrict__ eb,
    const ushort* __restrict__ Wb, const float* __restrict__ opb,
    const float* __restrict__ b1, const float* __restrict__ b2,
    float* __restrict__ out) {
  constexpr int IP = 136;  // K=128 pitch
  constexpr int HP = 264;  // K=256 pitch
  __shared__ ushort attB[16 * IP];  // ctx staging, then att bf16
  __shared__ ushort h1L[16 * HP];   // h1 bf16
  const int t = threadIdx.x;
  const int row0 = blockIdx.x * 16;

  for (int idx = t; idx < 16 * 16; idx += 256) {
    int r = idx >> 4, c = idx & 15;
    int i = row0 + r;
    int bb = eb[i];
    int qq0 = sq[bb];
    int lenq = sq[bb + 1] - qq0;
    int src = i;
    if (lenq > LQ && (i - qq0) >= LQ - 1) src = qq0 + lenq - 1;
    *(u16x8*)(attB + r * IP + c * 8) = *(const u16x8*)(CtxB + (size_t)src * H + c * 8);
  }
  __syncthreads();

  const int w = t >> 6, lane = t & 63, g = lane >> 4, l15 = lane & 15;
  const int row = row0 + l15;
  bf16x8 ca[4];
#pragma unroll
  for (int kc = 0; kc < 4; kc++)
    ca[kc] = *(const bf16x8*)(attB + l15 * IP + kc * 32 + g * 8);
  __syncthreads();   // attB free for att writes

  // phase A: att = ctx @ opw^T + opb + edge_attr  (2 ct tiles per wave)
  float att[2][4];
#pragma unroll
  for (int ci = 0; ci < 2; ci++) {
    int ct = w * 2 + ci;
    f32x4 acc = {0.f, 0.f, 0.f, 0.f};
#pragma unroll
    for (int kc = 0; kc < 4; kc++) {
      bf16x8 bw = *(const bf16x8*)(Wb + OPW_OFF + (size_t)(ct * 16 + l15) * H + kc * 32 + g * 8);
      acc = __builtin_amdgcn_mfma_f32_16x16x32_bf16(bw, ca[kc], acc, 0, 0, 0);
    }
    int oc = ct * 16 + 4 * g;
    float4 bo = *(const float4*)(opb + oc);
    float4 ea = *(const float4*)(edge_attr + (size_t)row * H + oc);
    ushort4 v;
    att[ci][0] = acc[0] + bo.x + ea.x; v.x = f2bf(att[ci][0]);
    att[ci][1] = acc[1] + bo.y + ea.y; v.y = f2bf(att[ci][1]);
    att[ci][2] = acc[2] + bo.z + ea.z; v.z = f2bf(att[ci][2]);
    att[ci][3] = acc[3] + bo.w + ea.w; v.w = f2bf(att[ci][3]);
    *(ushort4*)(attB + l15 * IP + oc) = v;
  }
  __syncthreads();

  // phase B: h1 = relu(att @ w1^T + b1)  (4 ct tiles per wave)
  bf16x8 aa[4];
#pragma unroll
  for (int kc = 0; kc < 4; kc++)
    aa[kc] = *(const bf16x8*)(attB + l15 * IP + kc * 32 + g * 8);
#pragma unroll
  for (int ci = 0; ci < 4; ci++) {
    int ct = w * 4 + ci;
    f32x4 acc = {0.f, 0.f, 0.f, 0.f};
#pragma unroll
    for (int kc = 0; kc < 4; kc++) {
      bf16x8 bw = *(const bf16x8*)(Wb + W1_OFF + (size_t)(ct * 16 + l15) * H + kc * 32 + g * 8);
      acc = __builtin_amdgcn_mfma_f32_16x16x32_bf16(bw, aa[kc], acc, 0, 0, 0);
    }
    int oc = ct * 16 + 4 * g;
    float4 bb = *(const float4*)(b1 + oc);
    ushort4 v;
    v.x = f2bf(fmaxf(acc[0] + bb.x, 0.f)); v.y = f2bf(fmaxf(acc[1] + bb.y, 0.f));
    v.z = f2bf(fmaxf(acc[2] + bb.z, 0.f)); v.w = f2bf(fmaxf(acc[3] + bb.w, 0.f));
    *(ushort4*)(h1L + l15 * HP + oc) = v;
  }
  __syncthreads();

  // phase C: out = att + h1 @ w2^T + b2  (same 2 ct tiles as phase A)
  bf16x8 ha[8];
#pragma unroll
  for (int kc = 0; kc < 8; kc++)
    ha[kc] = *(const bf16x8*)(h1L + l15 * HP + kc * 32 + g * 8);
#pragma unroll
  for (int ci = 0; ci < 2; ci++) {
    int ct = w * 2 + ci;
    f32x4 acc = {0.f, 0.f, 0.f, 0.f};
#pragma unroll
    for (int kc = 0; kc < 8; kc++) {
      bf16x8 bw = *(const bf16x8*)(Wb + W2_OFF + (size_t)(ct * 16 + l15) * 2 * H + kc * 32 + g * 8);
      acc = __builtin_amdgcn_mfma_f32_16x16x32_bf16(bw, ha[kc], acc, 0, 0, 0);
    }
    int oc = ct * 16 + 4 * g;
    float4 bb = *(const float4*)(b2 + oc);
    float4 o;
    o.x = att[ci][0] + acc[0] + bb.x;
    o.y = att[ci][1] + acc[1] + bb.y;
    o.z = att[ci][2] + acc[2] + bb.z;
    o.w = att[ci][3] + acc[3] + bb.w;
    *(float4*)(out + (size_t)row * H + oc) = o;
  }
}

extern "C" void kernel_launch(void* const* d_in, const int* in_sizes, int n_in,
                              void* d_out, int out_size, void* d_ws, size_t ws_size,
                              hipStream_t stream) {
  const float* edge_attr = (const float*)d_in[1];
  const int*   iel       = (const int*)d_in[2];
  const int*   ieb       = (const int*)d_in[3];
  const int*   eb        = (const int*)d_in[4];
  const float* in_proj_w = (const float*)d_in[5];
  const float* in_proj_b = (const float*)d_in[6];
  const float* opw       = (const float*)d_in[7];
  const float* opb       = (const float*)d_in[8];
  const float* w1        = (const float*)d_in[9];
  const float* b1        = (const float*)d_in[10];
  const float* w2        = (const float*)d_in[11];
  const float* b2        = (const float*)d_in[12];
  float* out = (float*)d_out;

  char* ws = (char*)d_ws;
  int* sq = (int*)ws;
  int* sk = (int*)(ws + 2048);
  ushort* CtxB = (ushort*)(ws + 4096);            // E*H bf16
  ushort* Wb   = CtxB + (size_t)E * H;            // 131072 bf16 weights
  ushort* Eb   = Wb + W_TOTAL;                    // E*H bf16 edge_attr

  k_starts_prep<<<dim3(2177), dim3(256), 0, stream>>>(eb, ieb, sq, sk, in_proj_w, opw, w1, w2, edge_attr, Wb, Eb);
  k_attn_fused<<<dim3(B, NH), dim3(256), 0, stream>>>(Eb, iel, Wb, in_proj_b, sq, sk, CtxB);
  k_out_ffn_mfma<<<dim3(E / 16), dim3(256), 0, stream>>>(CtxB, edge_attr, sq, eb, Wb, opb, b1, b2, out);
}

// Round 12
// 91.553 us; speedup vs baseline: 4.4349x; 1.0297x over previous
//
#include <hip/hip_runtime.h>
#include <hip/hip_bf16.h>

constexpr int B  = 256;
constexpr int E  = 16384;
constexpr int M  = 65536;
constexpr int H  = 128;
constexpr int NH = 4;
constexpr int HD = 32;
constexpr int LQ = 128;
constexpr int LK = 384;

// bf16 weight buffer offsets (elements)
constexpr int WQ_OFF  = 0;
constexpr int WK_OFF  = 16384;
constexpr int WV_OFF  = 32768;
constexpr int OPW_OFF = 49152;
constexpr int W1_OFF  = 65536;
constexpr int W2_OFF  = 98304;
constexpr int W_TOTAL = 131072;

typedef __attribute__((ext_vector_type(8))) short bf16x8;
typedef __attribute__((ext_vector_type(8))) unsigned short u16x8;
typedef __attribute__((ext_vector_type(4))) float f32x4;

__device__ __forceinline__ ushort f2bf(float x) {
  union { float f; unsigned u; } v; v.f = x;
  unsigned r = (v.u + 0x7FFFu + ((v.u >> 16) & 1u)) >> 16;
  return (ushort)r;
}

// ---------------- K1: starts + bf16 weights + bf16 edge_attr copy ----------------
__global__ __launch_bounds__(256) void k_starts_prep(
    const int* __restrict__ eb, const int* __restrict__ ieb,
    int* __restrict__ sq, int* __restrict__ sk,
    const float* __restrict__ in_proj_w, const float* __restrict__ opw,
    const float* __restrict__ w1, const float* __restrict__ w2,
    const float* __restrict__ edge_attr,
    ushort* __restrict__ Wb, ushort* __restrict__ Eb) {
  const int bx = blockIdx.x, t = threadIdx.x;
  if (bx == 0) {
    for (int i = t; i <= B; i += 256) {
      int lo = 0, hi = E;
      while (lo < hi) { int mid = (lo + hi) >> 1; if (eb[mid] < i) lo = mid + 1; else hi = mid; }
      sq[i] = lo;
      lo = 0; hi = M;
      while (lo < hi) { int mid = (lo + hi) >> 1; if (ieb[mid] < i) lo = mid + 1; else hi = mid; }
      sk[i] = lo;
    }
  } else if (bx <= 128) {
    int i = ((bx - 1) * 256 + t) * 4;
    if (i < W_TOTAL) {
      float4 v;
      if (i < OPW_OFF)      v = *(const float4*)(in_proj_w + i);
      else if (i < W1_OFF)  v = *(const float4*)(opw + (i - OPW_OFF));
      else if (i < W2_OFF)  v = *(const float4*)(w1 + (i - W1_OFF));
      else                  v = *(const float4*)(w2 + (i - W2_OFF));
      ushort4 o; o.x = f2bf(v.x); o.y = f2bf(v.y); o.z = f2bf(v.z); o.w = f2bf(v.w);
      *(ushort4*)(Wb + i) = o;
    }
  } else {
    int i = ((bx - 129) * 256 + t) * 4;   // E*H = 2M elems, 2048 blocks
    float4 v = *(const float4*)(edge_attr + i);
    ushort4 o; o.x = f2bf(v.x); o.y = f2bf(v.y); o.z = f2bf(v.z); o.w = f2bf(v.w);
    *(ushort4*)(Eb + i) = o;
  }
}

// ---------------- K2: fused QKV-projection + flash attention ----------------
// grid (B, NH), 256 threads = 4 waves. Projection into LDS as before; flash
// loop now processes 64 keys/iteration with K-frag prefetch.
__global__ __launch_bounds__(256) void k_attn_fused(
    const ushort* __restrict__ Eb, const int* __restrict__ iel,
    const ushort* __restrict__ Wb, const float* __restrict__ in_proj_b,
    const int* __restrict__ sq, const int* __restrict__ sk,
    ushort* __restrict__ CtxB) {
  constexpr int KP = 40;
  constexpr int QP = 40;
  constexpr int VP = 392;
  constexpr int PP = 72;   // 64 kk slots + pad, 16B-aligned pitch
  __shared__ ushort Kl[LK * KP];
  __shared__ ushort Ql[LQ * QP];
  __shared__ ushort VTl[HD * VP];
  __shared__ ushort Pl[4 * 16 * PP];

  const int b = blockIdx.x, h = blockIdx.y;
  const int t = threadIdx.x;
  const int q0 = sq[b], lenq = sq[b + 1] - q0;
  const int k0 = sk[b], lenk = sk[b + 1] - k0;
  const int nq = lenq < LQ ? lenq : LQ;
  const int nk = lenk < LK ? lenk : LK;
  const int nkc = (nk + 63) & ~63;     // 64-granular padding
  const int nqt = (nq + 15) >> 4;
  const int nkt = nkc >> 4;

  const int wave = t >> 6, lane = t & 63, g = lane >> 4, l15 = lane & 15;
  const int chb = h * HD;               // head channel base (32 ch)
  const ushort4 z4 = {0, 0, 0, 0};

  // ---- Q projection: per wave, qt tiles ----
  {
    bf16x8 wf[2][4];
#pragma unroll
    for (int ct = 0; ct < 2; ct++)
#pragma unroll
      for (int kc = 0; kc < 4; kc++)
        wf[ct][kc] = *(const bf16x8*)(Wb + WQ_OFF + (size_t)(chb + ct * 16 + l15) * H + kc * 32 + g * 8);
    for (int qt = wave; qt < nqt; qt += 4) {
      int slot = qt * 16 + l15;
      bool valid = slot < nq;
      int src = q0 + slot;
      if (lenq > LQ && slot == LQ - 1) src = q0 + lenq - 1;
      if (!valid) src = q0;
      bf16x8 rb[4];
#pragma unroll
      for (int kc = 0; kc < 4; kc++)
        rb[kc] = *(const bf16x8*)(Eb + (size_t)src * H + kc * 32 + g * 8);
#pragma unroll
      for (int ct = 0; ct < 2; ct++) {
        f32x4 acc = {0.f, 0.f, 0.f, 0.f};
#pragma unroll
        for (int kc = 0; kc < 4; kc++)
          acc = __builtin_amdgcn_mfma_f32_16x16x32_bf16(wf[ct][kc], rb[kc], acc, 0, 0, 0);
        ushort4 v = z4;
        if (valid) {
          float4 bb = *(const float4*)(in_proj_b + chb + ct * 16 + 4 * g);
          v.x = f2bf(acc[0] + bb.x); v.y = f2bf(acc[1] + bb.y);
          v.z = f2bf(acc[2] + bb.z); v.w = f2bf(acc[3] + bb.w);
        }
        *(ushort4*)(Ql + (qt * 16 + l15) * QP + ct * 16 + 4 * g) = v;
      }
    }
  }

  // ---- K,V projection: per wave, kt tiles (shared row gather) ----
  {
    bf16x8 wkf[2][4], wvf[2][4];
#pragma unroll
    for (int ct = 0; ct < 2; ct++)
#pragma unroll
      for (int kc = 0; kc < 4; kc++) {
        wkf[ct][kc] = *(const bf16x8*)(Wb + WK_OFF + (size_t)(chb + ct * 16 + l15) * H + kc * 32 + g * 8);
        wvf[ct][kc] = *(const bf16x8*)(Wb + WV_OFF + (size_t)(chb + ct * 16 + l15) * H + kc * 32 + g * 8);
      }
    for (int kt = wave; kt < nkt; kt += 4) {
      int slot = kt * 16 + l15;
      bool valid = slot < nk;
      int src = 0;
      if (valid) {
        int kj = k0 + slot;
        if (lenk > LK && slot == LK - 1) kj = k0 + lenk - 1;
        src = iel[kj];
      }
      bf16x8 rb[4];
#pragma unroll
      for (int kc = 0; kc < 4; kc++)
        rb[kc] = *(const bf16x8*)(Eb + (size_t)src * H + kc * 32 + g * 8);
      // K -> Kl row-major
#pragma unroll
      for (int ct = 0; ct < 2; ct++) {
        f32x4 acc = {0.f, 0.f, 0.f, 0.f};
#pragma unroll
        for (int kc = 0; kc < 4; kc++)
          acc = __builtin_amdgcn_mfma_f32_16x16x32_bf16(wkf[ct][kc], rb[kc], acc, 0, 0, 0);
        ushort4 v = z4;
        if (valid) {
          float4 bb = *(const float4*)(in_proj_b + H + chb + ct * 16 + 4 * g);
          v.x = f2bf(acc[0] + bb.x); v.y = f2bf(acc[1] + bb.y);
          v.z = f2bf(acc[2] + bb.z); v.w = f2bf(acc[3] + bb.w);
        }
        *(ushort4*)(Kl + (kt * 16 + l15) * KP + ct * 16 + 4 * g) = v;
      }
      // V -> VTl transposed (channel rows)
#pragma unroll
      for (int ct = 0; ct < 2; ct++) {
        f32x4 acc = {0.f, 0.f, 0.f, 0.f};
#pragma unroll
        for (int kc = 0; kc < 4; kc++)
          acc = __builtin_amdgcn_mfma_f32_16x16x32_bf16(wvf[ct][kc], rb[kc], acc, 0, 0, 0);
        if (valid) {
          float4 bb = *(const float4*)(in_proj_b + 2 * H + chb + ct * 16 + 4 * g);
          VTl[(ct * 16 + 4 * g + 0) * VP + kt * 16 + l15] = f2bf(acc[0] + bb.x);
          VTl[(ct * 16 + 4 * g + 1) * VP + kt * 16 + l15] = f2bf(acc[1] + bb.y);
          VTl[(ct * 16 + 4 * g + 2) * VP + kt * 16 + l15] = f2bf(acc[2] + bb.z);
          VTl[(ct * 16 + 4 * g + 3) * VP + kt * 16 + l15] = f2bf(acc[3] + bb.w);
        } else {
#pragma unroll
          for (int r = 0; r < 4; r++)
            VTl[(ct * 16 + 4 * g + r) * VP + kt * 16 + l15] = 0;
        }
      }
    }
  }
  __syncthreads();

  // ---- flash attention: 64 keys / iteration ----
  ushort* Pw = Pl + wave * 16 * PP;
  const float scale = 0.17677669529663687f;  // 1/sqrt(32)

  for (int qt = wave; qt < nqt; qt += 4) {
    bf16x8 bq = *(const bf16x8*)(Ql + (qt * 16 + l15) * QP + g * 8);
    f32x4 o0 = {0.f, 0.f, 0.f, 0.f}, o1 = {0.f, 0.f, 0.f, 0.f};
    float m = -3.0e38f, s = 0.f;
    bf16x8 a0 = {}, a1 = {}, a2 = {}, a3 = {};
    if (nk > 0) {
      a0 = *(const bf16x8*)(Kl + (l15) * KP + g * 8);
      a1 = *(const bf16x8*)(Kl + (16 + l15) * KP + g * 8);
      a2 = *(const bf16x8*)(Kl + (32 + l15) * KP + g * 8);
      a3 = *(const bf16x8*)(Kl + (48 + l15) * KP + g * 8);
    }
    for (int kc = 0; kc < nk; kc += 64) {
      f32x4 z = {0.f, 0.f, 0.f, 0.f};
      f32x4 st0 = __builtin_amdgcn_mfma_f32_16x16x32_bf16(a0, bq, z, 0, 0, 0);
      f32x4 st1 = __builtin_amdgcn_mfma_f32_16x16x32_bf16(a1, bq, z, 0, 0, 0);
      f32x4 st2 = __builtin_amdgcn_mfma_f32_16x16x32_bf16(a2, bq, z, 0, 0, 0);
      f32x4 st3 = __builtin_amdgcn_mfma_f32_16x16x32_bf16(a3, bq, z, 0, 0, 0);
      // prefetch next iteration's K A-frags (hidden under softmax)
      if (kc + 64 < nk) {
        a0 = *(const bf16x8*)(Kl + (kc + 64 + l15) * KP + g * 8);
        a1 = *(const bf16x8*)(Kl + (kc + 80 + l15) * KP + g * 8);
        a2 = *(const bf16x8*)(Kl + (kc + 96 + l15) * KP + g * 8);
        a3 = *(const bf16x8*)(Kl + (kc + 112 + l15) * KP + g * 8);
      }
      float p[16];
#pragma unroll
      for (int r = 0; r < 4; r++) {
        p[r]      = (kc + 4 * g + r < nk)      ? st0[r] * scale : -1e30f;
        p[4 + r]  = (kc + 16 + 4 * g + r < nk) ? st1[r] * scale : -1e30f;
        p[8 + r]  = (kc + 32 + 4 * g + r < nk) ? st2[r] * scale : -1e30f;
        p[12 + r] = (kc + 48 + 4 * g + r < nk) ? st3[r] * scale : -1e30f;
      }
      float pm = p[0];
#pragma unroll
      for (int r = 1; r < 16; r++) pm = fmaxf(pm, p[r]);
      pm = fmaxf(pm, __shfl_xor(pm, 16));
      pm = fmaxf(pm, __shfl_xor(pm, 32));
      float mn = fmaxf(m, pm);
      float corr = __expf(m - mn);
      float rs = 0.f;
#pragma unroll
      for (int r = 0; r < 16; r++) { p[r] = __expf(p[r] - mn); rs += p[r]; }
      rs += __shfl_xor(rs, 16);
      rs += __shfl_xor(rs, 32);
      s = s * corr + rs;
      m = mn;
      ushort4 w0, w1, w2, w3;
      w0.x = f2bf(p[0]);  w0.y = f2bf(p[1]);  w0.z = f2bf(p[2]);  w0.w = f2bf(p[3]);
      w1.x = f2bf(p[4]);  w1.y = f2bf(p[5]);  w1.z = f2bf(p[6]);  w1.w = f2bf(p[7]);
      w2.x = f2bf(p[8]);  w2.y = f2bf(p[9]);  w2.z = f2bf(p[10]); w2.w = f2bf(p[11]);
      w3.x = f2bf(p[12]); w3.y = f2bf(p[13]); w3.z = f2bf(p[14]); w3.w = f2bf(p[15]);
      __builtin_amdgcn_sched_barrier(0);
      *(ushort4*)(Pw + l15 * PP + 4 * g) = w0;
      *(ushort4*)(Pw + l15 * PP + 16 + 4 * g) = w1;
      *(ushort4*)(Pw + l15 * PP + 32 + 4 * g) = w2;
      *(ushort4*)(Pw + l15 * PP + 48 + 4 * g) = w3;
      asm volatile("s_waitcnt lgkmcnt(0)" ::: "memory");
      __builtin_amdgcn_sched_barrier(0);
      bf16x8 pb0 = *(const bf16x8*)(Pw + l15 * PP + 8 * g);
      bf16x8 pb1 = *(const bf16x8*)(Pw + l15 * PP + 32 + 8 * g);
      bf16x8 av00 = *(const bf16x8*)(VTl + l15 * VP + kc + 8 * g);
      bf16x8 av01 = *(const bf16x8*)(VTl + l15 * VP + kc + 32 + 8 * g);
      bf16x8 av10 = *(const bf16x8*)(VTl + (16 + l15) * VP + kc + 8 * g);
      bf16x8 av11 = *(const bf16x8*)(VTl + (16 + l15) * VP + kc + 32 + 8 * g);
#pragma unroll
      for (int r = 0; r < 4; r++) { o0[r] *= corr; o1[r] *= corr; }
      o0 = __builtin_amdgcn_mfma_f32_16x16x32_bf16(av00, pb0, o0, 0, 0, 0);
      o0 = __builtin_amdgcn_mfma_f32_16x16x32_bf16(av01, pb1, o0, 0, 0, 0);
      o1 = __builtin_amdgcn_mfma_f32_16x16x32_bf16(av10, pb0, o1, 0, 0, 0);
      o1 = __builtin_amdgcn_mfma_f32_16x16x32_bf16(av11, pb1, o1, 0, 0, 0);
    }
    int slot = qt * 16 + l15;
    if (slot < nq) {
      int qi = q0 + slot;
      if (lenq > LQ && slot == LQ - 1) qi = q0 + lenq - 1;
      ushort* outp = CtxB + (size_t)qi * H + chb;
      if (nk > 0) {
        float inv = 1.f / s;
        ushort4 v0, v1;
#pragma unroll
        for (int r = 0; r < 4; r++) { ((ushort*)&v0)[r] = f2bf(o0[r] * inv); ((ushort*)&v1)[r] = f2bf(o1[r] * inv); }
        *(ushort4*)(outp + 4 * g) = v0;
        *(ushort4*)(outp + 16 + 4 * g) = v1;
      } else {
        const float* bv = in_proj_b + 2 * H + chb;
        ushort4 v0, v1;
#pragma unroll
        for (int r = 0; r < 4; r++) { ((ushort*)&v0)[r] = f2bf(bv[4 * g + r]); ((ushort*)&v1)[r] = f2bf(bv[16 + 4 * g + r]); }
        *(ushort4*)(outp + 4 * g) = v0;
        *(ushort4*)(outp + 16 + 4 * g) = v1;
      }
    }
  }
}

// ---------------- K3: out-proj + residual + FFN (16-row blocks) ----------------
__global__ __launch_bounds__(256) void k_out_ffn_mfma(
    const ushort* __restrict__ CtxB, const float* __restrict__ edge_attr,
    const int* __restrict__ sq, const int* __restrict__ eb,
    const ushort* __restrict__ Wb, const float* __restrict__ opb,
    const float* __restrict__ b1, const float* __restrict__ b2,
    float* __restrict__ out) {
  constexpr int IP = 136;  // K=128 pitch
  constexpr int HP = 264;  // K=256 pitch
  __shared__ ushort attB[16 * IP];  // ctx staging, then att bf16
  __shared__ ushort h1L[16 * HP];   // h1 bf16
  const int t = threadIdx.x;
  const int row0 = blockIdx.x * 16;

  for (int idx = t; idx < 16 * 16; idx += 256) {
    int r = idx >> 4, c = idx & 15;
    int i = row0 + r;
    int bb = eb[i];
    int qq0 = sq[bb];
    int lenq = sq[bb + 1] - qq0;
    int src = i;
    if (lenq > LQ && (i - qq0) >= LQ - 1) src = qq0 + lenq - 1;
    *(u16x8*)(attB + r * IP + c * 8) = *(const u16x8*)(CtxB + (size_t)src * H + c * 8);
  }
  __syncthreads();

  const int w = t >> 6, lane = t & 63, g = lane >> 4, l15 = lane & 15;
  const int row = row0 + l15;
  bf16x8 ca[4];
#pragma unroll
  for (int kc = 0; kc < 4; kc++)
    ca[kc] = *(const bf16x8*)(attB + l15 * IP + kc * 32 + g * 8);
  __syncthreads();   // attB free for att writes

  // phase A: att = ctx @ opw^T + opb + edge_attr  (2 ct tiles per wave)
  float att[2][4];
#pragma unroll
  for (int ci = 0; ci < 2; ci++) {
    int ct = w * 2 + ci;
    f32x4 acc = {0.f, 0.f, 0.f, 0.f};
#pragma unroll
    for (int kc = 0; kc < 4; kc++) {
      bf16x8 bw = *(const bf16x8*)(Wb + OPW_OFF + (size_t)(ct * 16 + l15) * H + kc * 32 + g * 8);
      acc = __builtin_amdgcn_mfma_f32_16x16x32_bf16(bw, ca[kc], acc, 0, 0, 0);
    }
    int oc = ct * 16 + 4 * g;
    float4 bo = *(const float4*)(opb + oc);
    float4 ea = *(const float4*)(edge_attr + (size_t)row * H + oc);
    ushort4 v;
    att[ci][0] = acc[0] + bo.x + ea.x; v.x = f2bf(att[ci][0]);
    att[ci][1] = acc[1] + bo.y + ea.y; v.y = f2bf(att[ci][1]);
    att[ci][2] = acc[2] + bo.z + ea.z; v.z = f2bf(att[ci][2]);
    att[ci][3] = acc[3] + bo.w + ea.w; v.w = f2bf(att[ci][3]);
    *(ushort4*)(attB + l15 * IP + oc) = v;
  }
  __syncthreads();

  // phase B: h1 = relu(att @ w1^T + b1)  (4 ct tiles per wave)
  bf16x8 aa[4];
#pragma unroll
  for (int kc = 0; kc < 4; kc++)
    aa[kc] = *(const bf16x8*)(attB + l15 * IP + kc * 32 + g * 8);
#pragma unroll
  for (int ci = 0; ci < 4; ci++) {
    int ct = w * 4 + ci;
    f32x4 acc = {0.f, 0.f, 0.f, 0.f};
#pragma unroll
    for (int kc = 0; kc < 4; kc++) {
      bf16x8 bw = *(const bf16x8*)(Wb + W1_OFF + (size_t)(ct * 16 + l15) * H + kc * 32 + g * 8);
      acc = __builtin_amdgcn_mfma_f32_16x16x32_bf16(bw, aa[kc], acc, 0, 0, 0);
    }
    int oc = ct * 16 + 4 * g;
    float4 bb = *(const float4*)(b1 + oc);
    ushort4 v;
    v.x = f2bf(fmaxf(acc[0] + bb.x, 0.f)); v.y = f2bf(fmaxf(acc[1] + bb.y, 0.f));
    v.z = f2bf(fmaxf(acc[2] + bb.z, 0.f)); v.w = f2bf(fmaxf(acc[3] + bb.w, 0.f));
    *(ushort4*)(h1L + l15 * HP + oc) = v;
  }
  __syncthreads();

  // phase C: out = att + h1 @ w2^T + b2  (same 2 ct tiles as phase A)
  bf16x8 ha[8];
#pragma unroll
  for (int kc = 0; kc < 8; kc++)
    ha[kc] = *(const bf16x8*)(h1L + l15 * HP + kc * 32 + g * 8);
#pragma unroll
  for (int ci = 0; ci < 2; ci++) {
    int ct = w * 2 + ci;
    f32x4 acc = {0.f, 0.f, 0.f, 0.f};
#pragma unroll
    for (int kc = 0; kc < 8; kc++) {
      bf16x8 bw = *(const bf16x8*)(Wb + W2_OFF + (size_t)(ct * 16 + l15) * 2 * H + kc * 32 + g * 8);
      acc = __builtin_amdgcn_mfma_f32_16x16x32_bf16(bw, ha[kc], acc, 0, 0, 0);
    }
    int oc = ct * 16 + 4 * g;
    float4 bb = *(const float4*)(b2 + oc);
    float4 o;
    o.x = att[ci][0] + acc[0] + bb.x;
    o.y = att[ci][1] + acc[1] + bb.y;
    o.z = att[ci][2] + acc[2] + bb.z;
    o.w = att[ci][3] + acc[3] + bb.w;
    *(float4*)(out + (size_t)row * H + oc) = o;
  }
}

extern "C" void kernel_launch(void* const* d_in, const int* in_sizes, int n_in,
                              void* d_out, int out_size, void* d_ws, size_t ws_size,
                              hipStream_t stream) {
  const float* edge_attr = (const float*)d_in[1];
  const int*   iel       = (const int*)d_in[2];
  const int*   ieb       = (const int*)d_in[3];
  const int*   eb        = (const int*)d_in[4];
  const float* in_proj_w = (const float*)d_in[5];
  const float* in_proj_b = (const float*)d_in[6];
  const float* opw       = (const float*)d_in[7];
  const float* opb       = (const float*)d_in[8];
  const float* w1        = (const float*)d_in[9];
  const float* b1        = (const float*)d_in[10];
  const float* w2        = (const float*)d_in[11];
  const float* b2        = (const float*)d_in[12];
  float* out = (float*)d_out;

  char* ws = (char*)d_ws;
  int* sq = (int*)ws;
  int* sk = (int*)(ws + 2048);
  ushort* CtxB = (ushort*)(ws + 4096);            // E*H bf16
  ushort* Wb   = CtxB + (size_t)E * H;            // 131072 bf16 weights
  ushort* Eb   = Wb + W_TOTAL;                    // E*H bf16 edge_attr

  k_starts_prep<<<dim3(2177), dim3(256), 0, stream>>>(eb, ieb, sq, sk, in_proj_w, opw, w1, w2, edge_attr, Wb, Eb);
  k_attn_fused<<<dim3(B, NH), dim3(256), 0, stream>>>(Eb, iel, Wb, in_proj_b, sq, sk, CtxB);
  k_out_ffn_mfma<<<dim3(E / 16), dim3(256), 0, stream>>>(CtxB, edge_attr, sq, eb, Wb, opb, b1, b2, out);
}